// Round 9
// baseline (301.830 us; speedup 1.0000x reference)
//
#include <hip/hip_runtime.h>
#include <stdint.h>

typedef unsigned int uint;
typedef unsigned short ushort_t;

#define NPTS 500000
#define NC 256
#define SPAIRS 600000
#define FS 14
#define F3 2744            // 14^3
#define VOXT (NC * F3)     // 702464
#define STRIP 343          // F3/8 voxels per k_out block
#define PCAP 3072          // LDS pid-stage capacity (max pairs/strip ~2.6K avg 293)
#define NBLK (NC * 8)      // k_out grid

// ---------- helpers ----------
__device__ __forceinline__ uint encF(float f) {
    uint u = __float_as_uint(f);
    return (u & 0x80000000u) ? ~u : (u | 0x80000000u);
}
__device__ __forceinline__ float decF(uint e) {
    uint u = (e & 0x80000000u) ? (e ^ 0x80000000u) : ~e;
    return __uint_as_float(u);
}
// ids may arrive as int32 (jax x64 off) or int64. Sorted cids: mid values ~128,
// so for int64 the odd int32 words (high) are 0; for int32 they're nonzero.
__device__ __forceinline__ uint detect64(const void* cids) {
    const int* p = (const int*)cids;
    int z = 0;
    #pragma unroll
    for (int k = 0; k < 5; ++k) z += (p[300001 + 2 * k] == 0) ? 1 : 0;
    return (z >= 3) ? 1u : 0u;
}
__device__ __forceinline__ int loadId(const void* p, int i, uint is64) {
    return is64 ? (int)((const long long*)p)[i] : ((const int*)p)[i];
}

// ---------- kernel 1: per-cluster count/sum(f64)/min/max + cache gathered coords ----------
// min stored as NEGATED monotonic encodings (atomicMax, 0-init) -> no 0xFF memset.
__global__ __launch_bounds__(256) void k_stats(const void* cids, const void* pids,
        const float* __restrict__ coords,
        double* gsum, uint* gcnt, uint* gminN, uint* gmax, float* __restrict__ ccoord) {
    __shared__ double sSum[NC][3];
    __shared__ uint   sCnt[NC];
    __shared__ uint   sMinN[NC][3];
    __shared__ uint   sMax[NC][3];
    int tid = threadIdx.x;
    for (int c = tid; c < NC; c += 256) {
        sCnt[c] = 0u;
        for (int d = 0; d < 3; ++d) { sSum[c][d] = 0.0; sMinN[c][d] = 0u; sMax[c][d] = 0u; }
    }
    __syncthreads();
    uint is64 = detect64(cids);
    int s = blockIdx.x * 256 + tid;
    bool valid = s < SPAIRS;
    int sc = valid ? s : SPAIRS - 1;
    int cid = loadId(cids, sc, is64);
    int pid = loadId(pids, sc, is64);
    float x = coords[3 * pid + 0];
    float y = coords[3 * pid + 1];
    float z = coords[3 * pid + 2];
    if (valid) {               // cache gathered coords contiguously for k_vox
        ccoord[3 * s + 0] = x;
        ccoord[3 * s + 1] = y;
        ccoord[3 * s + 2] = z;
    }
    int lane = tid & 63;
    int cid0 = __shfl(cid, 0, 64), cid63 = __shfl(cid, 63, 64);
    if (cid0 == cid63) {
        uint nval = (uint)__popcll(__ballot(valid));
        double dx = valid ? (double)x : 0.0;
        double dy = valid ? (double)y : 0.0;
        double dz = valid ? (double)z : 0.0;
        float mnx = valid ? x : INFINITY,  mny = valid ? y : INFINITY,  mnz = valid ? z : INFINITY;
        float mxx = valid ? x : -INFINITY, mxy = valid ? y : -INFINITY, mxz = valid ? z : -INFINITY;
        #pragma unroll
        for (int st = 1; st < 64; st <<= 1) {
            dx += __shfl_xor(dx, st, 64);
            dy += __shfl_xor(dy, st, 64);
            dz += __shfl_xor(dz, st, 64);
            mnx = fminf(mnx, __shfl_xor(mnx, st, 64));
            mny = fminf(mny, __shfl_xor(mny, st, 64));
            mnz = fminf(mnz, __shfl_xor(mnz, st, 64));
            mxx = fmaxf(mxx, __shfl_xor(mxx, st, 64));
            mxy = fmaxf(mxy, __shfl_xor(mxy, st, 64));
            mxz = fmaxf(mxz, __shfl_xor(mxz, st, 64));
        }
        if (lane == 0 && nval) {
            atomicAdd(&sCnt[cid0], nval);
            unsafeAtomicAdd(&sSum[cid0][0], dx);
            unsafeAtomicAdd(&sSum[cid0][1], dy);
            unsafeAtomicAdd(&sSum[cid0][2], dz);
            atomicMax(&sMinN[cid0][0], ~encF(mnx)); atomicMax(&sMinN[cid0][1], ~encF(mny)); atomicMax(&sMinN[cid0][2], ~encF(mnz));
            atomicMax(&sMax[cid0][0], encF(mxx));   atomicMax(&sMax[cid0][1], encF(mxy));   atomicMax(&sMax[cid0][2], encF(mxz));
        }
    } else if (valid) {
        atomicAdd(&sCnt[cid], 1u);
        unsafeAtomicAdd(&sSum[cid][0], (double)x);
        unsafeAtomicAdd(&sSum[cid][1], (double)y);
        unsafeAtomicAdd(&sSum[cid][2], (double)z);
        atomicMax(&sMinN[cid][0], ~encF(x)); atomicMax(&sMinN[cid][1], ~encF(y)); atomicMax(&sMinN[cid][2], ~encF(z));
        atomicMax(&sMax[cid][0], encF(x));   atomicMax(&sMax[cid][1], encF(y));   atomicMax(&sMax[cid][2], encF(z));
    }
    __syncthreads();
    for (int c = tid; c < NC; c += 256) {
        if (sCnt[c]) {
            atomicAdd(&gcnt[c], sCnt[c]);
            for (int d = 0; d < 3; ++d) {
                unsafeAtomicAdd(&gsum[c * 3 + d], sSum[c][d]);
                atomicMax(&gminN[c * 3 + d], sMinN[c][d]);
                atomicMax(&gmax[c * 3 + d], sMax[c][d]);
            }
        }
    }
}

// ---------- kernel 2: per-cluster mean/scale/offset (double) + parallel prefix for coff ----------
__global__ void k_params(const double* gsum, const uint* gcnt, const uint* gminN,
                         const uint* gmax, double* params, int* coff) {
    __shared__ uint wsum[4];
    int c = threadIdx.x;                 // exactly 256 threads
    uint n = gcnt[c];
    double mean[3] = {0, 0, 0}, off[3] = {0, 0, 0}, scale = 50.0;
    if (n) {
        double dn = (double)n;
        double r = 0.0, mn[3];
        for (int d = 0; d < 3; ++d) {
            mean[d] = gsum[c * 3 + d] / dn;
            mn[d] = (double)decF(~gminN[c * 3 + d]) - mean[d];
            double mx = (double)decF(gmax[c * 3 + d]) - mean[d];
            double ext = (mx - mn[d]) / (double)FS;
            r = fmax(r, ext);
        }
        double sr = 1.0 / r - 0.01;      // r==0 -> inf -> clamp to 50
        scale = fmin(sr, 50.0);
        for (int d = 0; d < 3; ++d) off[d] = -(mn[d] * scale);
    }
    params[c * 8 + 0] = mean[0]; params[c * 8 + 1] = mean[1]; params[c * 8 + 2] = mean[2];
    params[c * 8 + 3] = scale;
    params[c * 8 + 4] = off[0];  params[c * 8 + 5] = off[1];  params[c * 8 + 6] = off[2];
    params[c * 8 + 7] = 0.0;

    uint incl = n;
    #pragma unroll
    for (int d = 1; d < 64; d <<= 1) {
        uint y = __shfl_up(incl, d, 64);
        if ((c & 63) >= d) incl += y;
    }
    int w = c >> 6;
    if ((c & 63) == 63) wsum[w] = incl;
    __syncthreads();
    uint woff = 0;
    #pragma unroll
    for (int i = 0; i < 4; ++i) if (i < w) woff += wsum[i];
    coff[c] = (int)(incl - n + woff);
    if (c == 255) coff[NC] = (int)(incl + woff);
}

// ---------- kernel 3: voxel id + rank + per-voxel count (fully coalesced reads) ----------
__global__ __launch_bounds__(256) void k_vox(const void* cids,
        const float* __restrict__ ccoord, const double* __restrict__ params,
        ushort_t* vidl, ushort_t* rankl, uint* vptr) {
    int s = blockIdx.x * blockDim.x + threadIdx.x;
    if (s >= SPAIRS) return;
    uint is64 = detect64(cids);
    int cid = loadId(cids, s, is64);
    const double* P = params + cid * 8;
    float cx = ccoord[3 * s + 0];
    float cy = ccoord[3 * s + 1];
    float cz = ccoord[3 * s + 2];
    double vx = ((double)cx - P[0]) * P[3] + P[4];
    double vy = ((double)cy - P[1]) * P[3] + P[5];
    double vz = ((double)cz - P[2]) * P[3] + P[6];
    int ix = (int)floor(vx); ix = ix < 0 ? 0 : (ix > FS - 1 ? FS - 1 : ix);
    int iy = (int)floor(vy); iy = iy < 0 ? 0 : (iy > FS - 1 ? FS - 1 : iy);
    int iz = (int)floor(vz); iz = iz < 0 ? 0 : (iz > FS - 1 ? FS - 1 : iz);
    int v = (ix * FS + iy) * FS + iz;
    vidl[s] = (ushort_t)v;
    uint r = atomicAdd(&vptr[cid * F3 + v], 1u);   // rank within voxel
    rankl[s] = (ushort_t)r;
}

// ---------- kernel 4: per-cluster exclusive scan of vptr (+coff base) + sentinel + agg zero ----------
__global__ __launch_bounds__(256) void k_scan(const int* coff, uint* vptr, uint* agg) {
    __shared__ uint wsum[4];
    int c = blockIdx.x, t = threadIdx.x;
    uint* base = vptr + c * F3;
    int b0 = t * 11;                 // 11*256 = 2816 >= F3
    uint v[11];
    uint s = 0;
    #pragma unroll
    for (int i = 0; i < 11; ++i) {
        int idx = b0 + i;
        uint x = (idx < F3) ? base[idx] : 0u;
        v[i] = s;
        s += x;
    }
    uint run = s;
    #pragma unroll
    for (int d = 1; d < 64; d <<= 1) {
        uint y = __shfl_up(run, d, 64);
        if ((t & 63) >= d) run += y;
    }
    int w = t >> 6;
    if ((t & 63) == 63) wsum[w] = run;
    __syncthreads();
    uint woff = 0;
    #pragma unroll
    for (int i = 0; i < 4; ++i) if (i < w) woff += wsum[i];
    uint excl = run - s + woff + (uint)coff[c];
    #pragma unroll
    for (int i = 0; i < 11; ++i) {
        int idx = b0 + i;
        if (idx < F3) base[idx] = excl + v[i];   // exclusive start per voxel
    }
    if (c == 255 && t == 0) vptr[VOXT] = (uint)coff[NC];   // sentinel
    if (t < 32) agg[c * 32 + t] = 0u;                      // agg-enc zero
}

// ---------- kernel 5: deterministic scatter: spid = pair pids sorted by (cluster,voxel) ----------
__global__ __launch_bounds__(256) void k_scatter(const void* cids, const void* pids,
        const ushort_t* vidl, const ushort_t* rankl, const uint* vptr, int* spid) {
    int s = blockIdx.x * blockDim.x + threadIdx.x;
    if (s >= SPAIRS) return;
    uint is64 = detect64(cids);
    int cid = loadId(cids, s, is64);
    int pid = loadId(pids, s, is64);
    int vid = cid * F3 + (int)vidl[s];
    uint pos = vptr[vid] + (uint)rankl[s];
    spid[pos] = pid;
}

// ---------- kernel 6: float4 channel-group voxel mean + agg max + fused agg finalize ----------
// Thread owns (voxel, 4-channel group): all hot loads/stores are float4 with
// 32-bit offsets -> ~4x less VALU per element than scalar-channel version.
// 2 voxels/thread/iter -> 4 independent float4 feats loads in flight.
__global__ __launch_bounds__(256) void k_out(const float4* __restrict__ feats4,
        const uint* __restrict__ vptr, const int* __restrict__ spid,
        float* __restrict__ out, uint* __restrict__ agg, uint* __restrict__ done) {
    __shared__ uint  sVptr[344];
    __shared__ int   sPid[PCAP];
    __shared__ float sMxA[32][8][4];
    __shared__ uint  sTicket;
    int b = blockIdx.x;
    int xcd = b & 7, r = b >> 3;
    int c = xcd * 32 + (r >> 3);     // cluster (XCD-swizzled)
    int p = r & 7;                   // eighth
    int t = threadIdx.x;
    int vid0 = c * F3 + p * STRIP;

    sVptr[t] = vptr[vid0 + t];
    if (t < 88) sVptr[256 + t] = vptr[vid0 + 256 + t];
    if (t == 0) sPid[0] = 0;                     // np==0 safety
    __syncthreads();
    uint S0 = sVptr[0], S1 = sVptr[343];
    int np = (int)(S1 - S0);
    bool fits = np <= PCAP;
    if (fits) for (int i = t; i < np; i += 256) sPid[i] = spid[S0 + i];
    __syncthreads();

    int vox = t >> 3;                // voxel slot 0..31
    int chg = t & 7;                 // float4 channel group
    float4 mx = make_float4(-INFINITY, -INFINITY, -INFINITY, -INFINITY);

    #pragma unroll 2
    for (int jb = 0; jb < 6; ++jb) {
        int v0 = vox + 64 * jb, v1 = v0 + 32;    // 12 strided voxels/thread total
        bool ok0 = v0 < STRIP, ok1 = v1 < STRIP;
        int vc0 = ok0 ? v0 : 342, vc1 = ok1 ? v1 : 342;
        uint s00 = sVptr[vc0]; uint cn0 = ok0 ? (sVptr[vc0 + 1] - s00) : 0u;
        uint s10 = sVptr[vc1]; uint cn1 = ok1 ? (sVptr[vc1 + 1] - s10) : 0u;
        uint i00 = s00 - S0, i10 = s10 - S0;
        uint a0 = (cn0 >= 1) ? i00 : 0u;  uint b0 = (cn0 >= 2) ? (i00 + 1) : a0;
        uint a1 = (cn1 >= 1) ? i10 : 0u;  uint b1 = (cn1 >= 2) ? (i10 + 1) : a1;
        int p00 = fits ? sPid[a0] : spid[S0 + a0];
        int p01 = fits ? sPid[b0] : spid[S0 + b0];
        int p10 = fits ? sPid[a1] : spid[S0 + a1];
        int p11 = fits ? sPid[b1] : spid[S0 + b1];
        float4 f00 = feats4[(uint)p00 * 8u + (uint)chg];   // 4 independent 16B loads
        float4 f01 = feats4[(uint)p01 * 8u + (uint)chg];
        float4 f10 = feats4[(uint)p10 * 8u + (uint)chg];
        float4 f11 = feats4[(uint)p11 * 8u + (uint)chg];

        float4 acc0, acc1;
        acc0.x = ((cn0 >= 1) ? f00.x : 0.f) + ((cn0 >= 2) ? f01.x : 0.f);
        acc0.y = ((cn0 >= 1) ? f00.y : 0.f) + ((cn0 >= 2) ? f01.y : 0.f);
        acc0.z = ((cn0 >= 1) ? f00.z : 0.f) + ((cn0 >= 2) ? f01.z : 0.f);
        acc0.w = ((cn0 >= 1) ? f00.w : 0.f) + ((cn0 >= 2) ? f01.w : 0.f);
        acc1.x = ((cn1 >= 1) ? f10.x : 0.f) + ((cn1 >= 2) ? f11.x : 0.f);
        acc1.y = ((cn1 >= 1) ? f10.y : 0.f) + ((cn1 >= 2) ? f11.y : 0.f);
        acc1.z = ((cn1 >= 1) ? f10.z : 0.f) + ((cn1 >= 2) ? f11.z : 0.f);
        acc1.w = ((cn1 >= 1) ? f10.w : 0.f) + ((cn1 >= 2) ? f11.w : 0.f);
        if (cn0 >= 1) { mx.x = fmaxf(mx.x, f00.x); mx.y = fmaxf(mx.y, f00.y); mx.z = fmaxf(mx.z, f00.z); mx.w = fmaxf(mx.w, f00.w); }
        if (cn0 >= 2) { mx.x = fmaxf(mx.x, f01.x); mx.y = fmaxf(mx.y, f01.y); mx.z = fmaxf(mx.z, f01.z); mx.w = fmaxf(mx.w, f01.w); }
        if (cn1 >= 1) { mx.x = fmaxf(mx.x, f10.x); mx.y = fmaxf(mx.y, f10.y); mx.z = fmaxf(mx.z, f10.z); mx.w = fmaxf(mx.w, f10.w); }
        if (cn1 >= 2) { mx.x = fmaxf(mx.x, f11.x); mx.y = fmaxf(mx.y, f11.y); mx.z = fmaxf(mx.z, f11.z); mx.w = fmaxf(mx.w, f11.w); }

        if (cn0 > 2) {                         // rare tails (~5.5% of voxels)
            for (uint q = 2; q < cn0; ++q) {
                int pq = fits ? sPid[i00 + q] : spid[S0 + i00 + q];
                float4 fq = feats4[(uint)pq * 8u + (uint)chg];
                acc0.x += fq.x; acc0.y += fq.y; acc0.z += fq.z; acc0.w += fq.w;
                mx.x = fmaxf(mx.x, fq.x); mx.y = fmaxf(mx.y, fq.y); mx.z = fmaxf(mx.z, fq.z); mx.w = fmaxf(mx.w, fq.w);
            }
        }
        if (cn1 > 2) {
            for (uint q = 2; q < cn1; ++q) {
                int pq = fits ? sPid[i10 + q] : spid[S0 + i10 + q];
                float4 fq = feats4[(uint)pq * 8u + (uint)chg];
                acc1.x += fq.x; acc1.y += fq.y; acc1.z += fq.z; acc1.w += fq.w;
                mx.x = fmaxf(mx.x, fq.x); mx.y = fmaxf(mx.y, fq.y); mx.z = fmaxf(mx.z, fq.z); mx.w = fmaxf(mx.w, fq.w);
            }
        }
        if (ok0) {
            float inv = __builtin_amdgcn_rcpf(cn0 ? (float)cn0 : 1.f);
            float4 rr; rr.x = acc0.x * inv; rr.y = acc0.y * inv; rr.z = acc0.z * inv; rr.w = acc0.w * inv;
            *(float4*)(out + (uint)(vid0 + v0) * 32u + (uint)chg * 4u) = rr;
        }
        if (ok1) {
            float inv = __builtin_amdgcn_rcpf(cn1 ? (float)cn1 : 1.f);
            float4 rr; rr.x = acc1.x * inv; rr.y = acc1.y * inv; rr.z = acc1.z * inv; rr.w = acc1.w * inv;
            *(float4*)(out + (uint)(vid0 + v1) * 32u + (uint)chg * 4u) = rr;
        }
    }

    sMxA[vox][chg][0] = mx.x; sMxA[vox][chg][1] = mx.y;
    sMxA[vox][chg][2] = mx.z; sMxA[vox][chg][3] = mx.w;
    __syncthreads();
    if (t < 32) {                    // t = channel; chg = t>>2, elem = t&3
        float m = -INFINITY;
        #pragma unroll
        for (int v = 0; v < 32; ++v) m = fmaxf(m, sMxA[v][t >> 2][t & 3]);
        if (m != -INFINITY) atomicMax(&agg[c * 32 + t], encF(m));
    }

    // fused agg finalize: last block decodes (replaces k_aggfin launch)
    __threadfence();
    if (t == 0) sTicket = atomicAdd(done, 1u);
    __syncthreads();
    if (sTicket == NBLK - 1) {
        __threadfence();
        for (int i = t; i < NC * 32; i += 256) {
            uint e = agg[i];
            float f = decF(e);
            if (e == 0u || f == -INFINITY) f = 0.0f;
            ((float*)agg)[i] = f;
        }
    }
}

extern "C" void kernel_launch(void* const* d_in, const int* in_sizes, int n_in,
                              void* d_out, int out_size, void* d_ws, size_t ws_size,
                              hipStream_t stream) {
    const float* feats  = (const float*)d_in[0];
    const float* coords = (const float*)d_in[1];
    const void*  cids   = d_in[2];
    const void*  pids   = d_in[3];
    float* out = (float*)d_out;
    char* ws = (char*)d_ws;

    // ws layout (bytes), total 12,440,704:
    //   0         double gsum[256*3]       (6144)    } zero
    //   6144      uint   gcnt[256]         (1024)    } zero
    //   7168      uint   gmax[256*3]       (3072)    } zero
    //   10240     uint   vptr[VOXT+1]      (2809860) } zero -> pad 2820160
    //     2820144 uint   done              (in vptr pad, zeroed)
    //   2820160   uint   gminN[256*3]      (3072)    } zero (negated encodings)
    //   2823232   double params[256*8]     (16384)
    //   2839616   int    coff[257]         (1028 -> pad 2840704)
    //   2840704   u16    vidl[SPAIRS]      (1200000) -> 4040704
    //   4040704   u16    rankl[SPAIRS]     (1200000) -> 5240704
    //   5240704   float  ccoord[3*SPAIRS]  (7200000) -> 12440704
    //             int    spid[SPAIRS]      (2400000) ALIASES ccoord (dead after k_vox)
    double*   gsum   = (double*)(ws + 0);
    uint*     gcnt   = (uint*)(ws + 6144);
    uint*     gmax   = (uint*)(ws + 7168);
    uint*     vptr   = (uint*)(ws + 10240);
    uint*     done   = (uint*)(ws + 2820144);
    uint*     gminN  = (uint*)(ws + 2820160);
    double*   params = (double*)(ws + 2823232);
    int*      coff   = (int*)(ws + 2839616);
    ushort_t* vidl   = (ushort_t*)(ws + 2840704);
    ushort_t* rankl  = (ushort_t*)(ws + 4040704);
    float*    ccoord = (float*)(ws + 5240704);
    int*      spid   = (int*)(ws + 5240704);     // alias: ccoord dead before k_scatter
    uint*     agg    = (uint*)(out + (size_t)VOXT * 32);

    hipMemsetAsync(ws, 0, 2823232, stream);      // gsum..gminN (incl. done counter)

    int nb = (SPAIRS + 255) / 256;   // 2344
    k_stats<<<nb, 256, 0, stream>>>(cids, pids, coords, gsum, gcnt, gminN, gmax, ccoord);
    k_params<<<1, 256, 0, stream>>>(gsum, gcnt, gminN, gmax, params, coff);
    k_vox<<<nb, 256, 0, stream>>>(cids, ccoord, params, vidl, rankl, vptr);
    k_scan<<<NC, 256, 0, stream>>>(coff, vptr, agg);
    k_scatter<<<nb, 256, 0, stream>>>(cids, pids, vidl, rankl, vptr, spid);
    k_out<<<NBLK, 256, 0, stream>>>((const float4*)feats, vptr, spid, out, agg, done);
}

// Round 10
// 97.687 us; speedup vs baseline: 3.0898x; 3.0898x over previous
//
#include <hip/hip_runtime.h>
#include <stdint.h>

typedef unsigned int uint;
typedef unsigned short ushort_t;

#define NPTS 500000
#define NC 256
#define SPAIRS 600000
#define FS 14
#define F3 2744            // 14^3
#define VOXT (NC * F3)     // 702464
#define STRIP 343          // F3/8 voxels per k_out block
#define PCAP 3072          // LDS pid-stage capacity (max pairs/strip ~2.6K avg 293)
#define NBLK (NC * 8)      // k_out grid

// ---------- helpers ----------
__device__ __forceinline__ uint encF(float f) {
    uint u = __float_as_uint(f);
    return (u & 0x80000000u) ? ~u : (u | 0x80000000u);
}
__device__ __forceinline__ float decF(uint e) {
    uint u = (e & 0x80000000u) ? (e ^ 0x80000000u) : ~e;
    return __uint_as_float(u);
}
// ids may arrive as int32 (jax x64 off) or int64. Sorted cids: mid values ~128,
// so for int64 the odd int32 words (high) are 0; for int32 they're nonzero.
__device__ __forceinline__ uint detect64(const void* cids) {
    const int* p = (const int*)cids;
    int z = 0;
    #pragma unroll
    for (int k = 0; k < 5; ++k) z += (p[300001 + 2 * k] == 0) ? 1 : 0;
    return (z >= 3) ? 1u : 0u;
}
__device__ __forceinline__ int loadId(const void* p, int i, uint is64) {
    return is64 ? (int)((const long long*)p)[i] : ((const int*)p)[i];
}

// ---------- kernel 1: per-cluster count/sum(f64)/min/max + cache gathered coords ----------
// min stored as NEGATED monotonic encodings (atomicMax, 0-init) -> no 0xFF memset.
__global__ __launch_bounds__(256) void k_stats(const void* cids, const void* pids,
        const float* __restrict__ coords,
        double* gsum, uint* gcnt, uint* gminN, uint* gmax, float* __restrict__ ccoord) {
    __shared__ double sSum[NC][3];
    __shared__ uint   sCnt[NC];
    __shared__ uint   sMinN[NC][3];
    __shared__ uint   sMax[NC][3];
    int tid = threadIdx.x;
    for (int c = tid; c < NC; c += 256) {
        sCnt[c] = 0u;
        for (int d = 0; d < 3; ++d) { sSum[c][d] = 0.0; sMinN[c][d] = 0u; sMax[c][d] = 0u; }
    }
    __syncthreads();
    uint is64 = detect64(cids);
    int s = blockIdx.x * 256 + tid;
    bool valid = s < SPAIRS;
    int sc = valid ? s : SPAIRS - 1;
    int cid = loadId(cids, sc, is64);
    int pid = loadId(pids, sc, is64);
    float x = coords[3 * pid + 0];
    float y = coords[3 * pid + 1];
    float z = coords[3 * pid + 2];
    if (valid) {               // cache gathered coords contiguously for k_vox
        ccoord[3 * s + 0] = x;
        ccoord[3 * s + 1] = y;
        ccoord[3 * s + 2] = z;
    }
    int lane = tid & 63;
    int cid0 = __shfl(cid, 0, 64), cid63 = __shfl(cid, 63, 64);
    if (cid0 == cid63) {
        uint nval = (uint)__popcll(__ballot(valid));
        double dx = valid ? (double)x : 0.0;
        double dy = valid ? (double)y : 0.0;
        double dz = valid ? (double)z : 0.0;
        float mnx = valid ? x : INFINITY,  mny = valid ? y : INFINITY,  mnz = valid ? z : INFINITY;
        float mxx = valid ? x : -INFINITY, mxy = valid ? y : -INFINITY, mxz = valid ? z : -INFINITY;
        #pragma unroll
        for (int st = 1; st < 64; st <<= 1) {
            dx += __shfl_xor(dx, st, 64);
            dy += __shfl_xor(dy, st, 64);
            dz += __shfl_xor(dz, st, 64);
            mnx = fminf(mnx, __shfl_xor(mnx, st, 64));
            mny = fminf(mny, __shfl_xor(mny, st, 64));
            mnz = fminf(mnz, __shfl_xor(mnz, st, 64));
            mxx = fmaxf(mxx, __shfl_xor(mxx, st, 64));
            mxy = fmaxf(mxy, __shfl_xor(mxy, st, 64));
            mxz = fmaxf(mxz, __shfl_xor(mxz, st, 64));
        }
        if (lane == 0 && nval) {
            atomicAdd(&sCnt[cid0], nval);
            unsafeAtomicAdd(&sSum[cid0][0], dx);
            unsafeAtomicAdd(&sSum[cid0][1], dy);
            unsafeAtomicAdd(&sSum[cid0][2], dz);
            atomicMax(&sMinN[cid0][0], ~encF(mnx)); atomicMax(&sMinN[cid0][1], ~encF(mny)); atomicMax(&sMinN[cid0][2], ~encF(mnz));
            atomicMax(&sMax[cid0][0], encF(mxx));   atomicMax(&sMax[cid0][1], encF(mxy));   atomicMax(&sMax[cid0][2], encF(mxz));
        }
    } else if (valid) {
        atomicAdd(&sCnt[cid], 1u);
        unsafeAtomicAdd(&sSum[cid][0], (double)x);
        unsafeAtomicAdd(&sSum[cid][1], (double)y);
        unsafeAtomicAdd(&sSum[cid][2], (double)z);
        atomicMax(&sMinN[cid][0], ~encF(x)); atomicMax(&sMinN[cid][1], ~encF(y)); atomicMax(&sMinN[cid][2], ~encF(z));
        atomicMax(&sMax[cid][0], encF(x));   atomicMax(&sMax[cid][1], encF(y));   atomicMax(&sMax[cid][2], encF(z));
    }
    __syncthreads();
    for (int c = tid; c < NC; c += 256) {
        if (sCnt[c]) {
            atomicAdd(&gcnt[c], sCnt[c]);
            for (int d = 0; d < 3; ++d) {
                unsafeAtomicAdd(&gsum[c * 3 + d], sSum[c][d]);
                atomicMax(&gminN[c * 3 + d], sMinN[c][d]);
                atomicMax(&gmax[c * 3 + d], sMax[c][d]);
            }
        }
    }
}

// ---------- kernel 2: per-cluster mean/scale/offset (double) + parallel prefix for coff ----------
__global__ void k_params(const double* gsum, const uint* gcnt, const uint* gminN,
                         const uint* gmax, double* params, int* coff) {
    __shared__ uint wsum[4];
    int c = threadIdx.x;                 // exactly 256 threads
    uint n = gcnt[c];
    double mean[3] = {0, 0, 0}, off[3] = {0, 0, 0}, scale = 50.0;
    if (n) {
        double dn = (double)n;
        double r = 0.0, mn[3];
        for (int d = 0; d < 3; ++d) {
            mean[d] = gsum[c * 3 + d] / dn;
            mn[d] = (double)decF(~gminN[c * 3 + d]) - mean[d];
            double mx = (double)decF(gmax[c * 3 + d]) - mean[d];
            double ext = (mx - mn[d]) / (double)FS;
            r = fmax(r, ext);
        }
        double sr = 1.0 / r - 0.01;      // r==0 -> inf -> clamp to 50
        scale = fmin(sr, 50.0);
        for (int d = 0; d < 3; ++d) off[d] = -(mn[d] * scale);
    }
    params[c * 8 + 0] = mean[0]; params[c * 8 + 1] = mean[1]; params[c * 8 + 2] = mean[2];
    params[c * 8 + 3] = scale;
    params[c * 8 + 4] = off[0];  params[c * 8 + 5] = off[1];  params[c * 8 + 6] = off[2];
    params[c * 8 + 7] = 0.0;

    uint incl = n;
    #pragma unroll
    for (int d = 1; d < 64; d <<= 1) {
        uint y = __shfl_up(incl, d, 64);
        if ((c & 63) >= d) incl += y;
    }
    int w = c >> 6;
    if ((c & 63) == 63) wsum[w] = incl;
    __syncthreads();
    uint woff = 0;
    #pragma unroll
    for (int i = 0; i < 4; ++i) if (i < w) woff += wsum[i];
    coff[c] = (int)(incl - n + woff);
    if (c == 255) coff[NC] = (int)(incl + woff);
}

// ---------- kernel 3: voxel id + rank + per-voxel count (fully coalesced reads) ----------
__global__ __launch_bounds__(256) void k_vox(const void* cids,
        const float* __restrict__ ccoord, const double* __restrict__ params,
        ushort_t* vidl, ushort_t* rankl, uint* vptr) {
    int s = blockIdx.x * blockDim.x + threadIdx.x;
    if (s >= SPAIRS) return;
    uint is64 = detect64(cids);
    int cid = loadId(cids, s, is64);
    const double* P = params + cid * 8;
    float cx = ccoord[3 * s + 0];
    float cy = ccoord[3 * s + 1];
    float cz = ccoord[3 * s + 2];
    double vx = ((double)cx - P[0]) * P[3] + P[4];
    double vy = ((double)cy - P[1]) * P[3] + P[5];
    double vz = ((double)cz - P[2]) * P[3] + P[6];
    int ix = (int)floor(vx); ix = ix < 0 ? 0 : (ix > FS - 1 ? FS - 1 : ix);
    int iy = (int)floor(vy); iy = iy < 0 ? 0 : (iy > FS - 1 ? FS - 1 : iy);
    int iz = (int)floor(vz); iz = iz < 0 ? 0 : (iz > FS - 1 ? FS - 1 : iz);
    int v = (ix * FS + iy) * FS + iz;
    vidl[s] = (ushort_t)v;
    uint r = atomicAdd(&vptr[cid * F3 + v], 1u);   // rank within voxel
    rankl[s] = (ushort_t)r;
}

// ---------- kernel 4: per-cluster exclusive scan of vptr (+coff base) + sentinel + agg zero ----------
__global__ __launch_bounds__(256) void k_scan(const int* coff, uint* vptr, uint* agg) {
    __shared__ uint wsum[4];
    int c = blockIdx.x, t = threadIdx.x;
    uint* base = vptr + c * F3;
    int b0 = t * 11;                 // 11*256 = 2816 >= F3
    uint v[11];
    uint s = 0;
    #pragma unroll
    for (int i = 0; i < 11; ++i) {
        int idx = b0 + i;
        uint x = (idx < F3) ? base[idx] : 0u;
        v[i] = s;
        s += x;
    }
    uint run = s;
    #pragma unroll
    for (int d = 1; d < 64; d <<= 1) {
        uint y = __shfl_up(run, d, 64);
        if ((t & 63) >= d) run += y;
    }
    int w = t >> 6;
    if ((t & 63) == 63) wsum[w] = run;
    __syncthreads();
    uint woff = 0;
    #pragma unroll
    for (int i = 0; i < 4; ++i) if (i < w) woff += wsum[i];
    uint excl = run - s + woff + (uint)coff[c];
    #pragma unroll
    for (int i = 0; i < 11; ++i) {
        int idx = b0 + i;
        if (idx < F3) base[idx] = excl + v[i];   // exclusive start per voxel
    }
    if (c == 255 && t == 0) vptr[VOXT] = (uint)coff[NC];   // sentinel
    if (t < 32) agg[c * 32 + t] = 0u;                      // agg-enc zero
}

// ---------- kernel 5: deterministic scatter: spid = pair pids sorted by (cluster,voxel) ----------
__global__ __launch_bounds__(256) void k_scatter(const void* cids, const void* pids,
        const ushort_t* vidl, const ushort_t* rankl, const uint* vptr, int* spid) {
    int s = blockIdx.x * blockDim.x + threadIdx.x;
    if (s >= SPAIRS) return;
    uint is64 = detect64(cids);
    int cid = loadId(cids, s, is64);
    int pid = loadId(pids, s, is64);
    int vid = cid * F3 + (int)vidl[s];
    uint pos = vptr[vid] + (uint)rankl[s];
    spid[pos] = pid;
}

// ---------- kernel 6: float4 channel-group voxel mean + agg max ----------
// Thread owns (voxel, 4-channel group): all hot loads/stores are float4 with
// 32-bit offsets. 2 voxels/thread/iter -> 4 independent float4 loads in flight.
// NO device-scope fences here (R9 lesson: threadfence in a 2048-block grid
// forces serialized per-XCD L2 writebacks -> ~200us of stall).
__global__ __launch_bounds__(256) void k_out(const float4* __restrict__ feats4,
        const uint* __restrict__ vptr, const int* __restrict__ spid,
        float* __restrict__ out, uint* __restrict__ agg) {
    __shared__ uint  sVptr[344];
    __shared__ int   sPid[PCAP];
    __shared__ float sMxA[32][8][4];
    int b = blockIdx.x;
    int xcd = b & 7, r = b >> 3;
    int c = xcd * 32 + (r >> 3);     // cluster (XCD-swizzled)
    int p = r & 7;                   // eighth
    int t = threadIdx.x;
    int vid0 = c * F3 + p * STRIP;

    sVptr[t] = vptr[vid0 + t];
    if (t < 88) sVptr[256 + t] = vptr[vid0 + 256 + t];
    if (t == 0) sPid[0] = 0;                     // np==0 safety
    __syncthreads();
    uint S0 = sVptr[0], S1 = sVptr[343];
    int np = (int)(S1 - S0);
    bool fits = np <= PCAP;
    if (fits) for (int i = t; i < np; i += 256) sPid[i] = spid[S0 + i];
    __syncthreads();

    int vox = t >> 3;                // voxel slot 0..31
    int chg = t & 7;                 // float4 channel group
    float4 mx = make_float4(-INFINITY, -INFINITY, -INFINITY, -INFINITY);

    #pragma unroll 2
    for (int jb = 0; jb < 6; ++jb) {
        int v0 = vox + 64 * jb, v1 = v0 + 32;    // 12 strided voxels/thread total
        bool ok0 = v0 < STRIP, ok1 = v1 < STRIP;
        int vc0 = ok0 ? v0 : 342, vc1 = ok1 ? v1 : 342;
        uint s00 = sVptr[vc0]; uint cn0 = ok0 ? (sVptr[vc0 + 1] - s00) : 0u;
        uint s10 = sVptr[vc1]; uint cn1 = ok1 ? (sVptr[vc1 + 1] - s10) : 0u;
        uint i00 = s00 - S0, i10 = s10 - S0;
        uint a0 = (cn0 >= 1) ? i00 : 0u;  uint b0 = (cn0 >= 2) ? (i00 + 1) : a0;
        uint a1 = (cn1 >= 1) ? i10 : 0u;  uint b1 = (cn1 >= 2) ? (i10 + 1) : a1;
        int p00 = fits ? sPid[a0] : spid[S0 + a0];
        int p01 = fits ? sPid[b0] : spid[S0 + b0];
        int p10 = fits ? sPid[a1] : spid[S0 + a1];
        int p11 = fits ? sPid[b1] : spid[S0 + b1];
        float4 f00 = feats4[(uint)p00 * 8u + (uint)chg];   // 4 independent 16B loads
        float4 f01 = feats4[(uint)p01 * 8u + (uint)chg];
        float4 f10 = feats4[(uint)p10 * 8u + (uint)chg];
        float4 f11 = feats4[(uint)p11 * 8u + (uint)chg];

        float4 acc0, acc1;
        acc0.x = ((cn0 >= 1) ? f00.x : 0.f) + ((cn0 >= 2) ? f01.x : 0.f);
        acc0.y = ((cn0 >= 1) ? f00.y : 0.f) + ((cn0 >= 2) ? f01.y : 0.f);
        acc0.z = ((cn0 >= 1) ? f00.z : 0.f) + ((cn0 >= 2) ? f01.z : 0.f);
        acc0.w = ((cn0 >= 1) ? f00.w : 0.f) + ((cn0 >= 2) ? f01.w : 0.f);
        acc1.x = ((cn1 >= 1) ? f10.x : 0.f) + ((cn1 >= 2) ? f11.x : 0.f);
        acc1.y = ((cn1 >= 1) ? f10.y : 0.f) + ((cn1 >= 2) ? f11.y : 0.f);
        acc1.z = ((cn1 >= 1) ? f10.z : 0.f) + ((cn1 >= 2) ? f11.z : 0.f);
        acc1.w = ((cn1 >= 1) ? f10.w : 0.f) + ((cn1 >= 2) ? f11.w : 0.f);
        if (cn0 >= 1) { mx.x = fmaxf(mx.x, f00.x); mx.y = fmaxf(mx.y, f00.y); mx.z = fmaxf(mx.z, f00.z); mx.w = fmaxf(mx.w, f00.w); }
        if (cn0 >= 2) { mx.x = fmaxf(mx.x, f01.x); mx.y = fmaxf(mx.y, f01.y); mx.z = fmaxf(mx.z, f01.z); mx.w = fmaxf(mx.w, f01.w); }
        if (cn1 >= 1) { mx.x = fmaxf(mx.x, f10.x); mx.y = fmaxf(mx.y, f10.y); mx.z = fmaxf(mx.z, f10.z); mx.w = fmaxf(mx.w, f10.w); }
        if (cn1 >= 2) { mx.x = fmaxf(mx.x, f11.x); mx.y = fmaxf(mx.y, f11.y); mx.z = fmaxf(mx.z, f11.z); mx.w = fmaxf(mx.w, f11.w); }

        if (cn0 > 2) {                         // rare tails (~5.5% of voxels)
            for (uint q = 2; q < cn0; ++q) {
                int pq = fits ? sPid[i00 + q] : spid[S0 + i00 + q];
                float4 fq = feats4[(uint)pq * 8u + (uint)chg];
                acc0.x += fq.x; acc0.y += fq.y; acc0.z += fq.z; acc0.w += fq.w;
                mx.x = fmaxf(mx.x, fq.x); mx.y = fmaxf(mx.y, fq.y); mx.z = fmaxf(mx.z, fq.z); mx.w = fmaxf(mx.w, fq.w);
            }
        }
        if (cn1 > 2) {
            for (uint q = 2; q < cn1; ++q) {
                int pq = fits ? sPid[i10 + q] : spid[S0 + i10 + q];
                float4 fq = feats4[(uint)pq * 8u + (uint)chg];
                acc1.x += fq.x; acc1.y += fq.y; acc1.z += fq.z; acc1.w += fq.w;
                mx.x = fmaxf(mx.x, fq.x); mx.y = fmaxf(mx.y, fq.y); mx.z = fmaxf(mx.z, fq.z); mx.w = fmaxf(mx.w, fq.w);
            }
        }
        if (ok0) {
            float inv = __builtin_amdgcn_rcpf(cn0 ? (float)cn0 : 1.f);
            float4 rr; rr.x = acc0.x * inv; rr.y = acc0.y * inv; rr.z = acc0.z * inv; rr.w = acc0.w * inv;
            *(float4*)(out + (uint)(vid0 + v0) * 32u + (uint)chg * 4u) = rr;
        }
        if (ok1) {
            float inv = __builtin_amdgcn_rcpf(cn1 ? (float)cn1 : 1.f);
            float4 rr; rr.x = acc1.x * inv; rr.y = acc1.y * inv; rr.z = acc1.z * inv; rr.w = acc1.w * inv;
            *(float4*)(out + (uint)(vid0 + v1) * 32u + (uint)chg * 4u) = rr;
        }
    }

    sMxA[vox][chg][0] = mx.x; sMxA[vox][chg][1] = mx.y;
    sMxA[vox][chg][2] = mx.z; sMxA[vox][chg][3] = mx.w;
    __syncthreads();
    if (t < 32) {                    // t = channel; chg = t>>2, elem = t&3
        float m = -INFINITY;
        #pragma unroll
        for (int v = 0; v < 32; ++v) m = fmaxf(m, sMxA[v][t >> 2][t & 3]);
        if (m != -INFINITY) atomicMax(&agg[c * 32 + t], encF(m));
    }
}

// ---------- kernel 7: agg finalize (decode; untouched/neginf -> 0) ----------
__global__ void k_aggfin(float* outbase) {
    int i = blockIdx.x * blockDim.x + threadIdx.x;     // < NC*32 exactly
    uint* a = (uint*)(outbase + (size_t)VOXT * 32);
    uint e = a[i];
    float f = decF(e);
    if (e == 0u || f == -INFINITY) f = 0.0f;
    ((float*)a)[i] = f;
}

extern "C" void kernel_launch(void* const* d_in, const int* in_sizes, int n_in,
                              void* d_out, int out_size, void* d_ws, size_t ws_size,
                              hipStream_t stream) {
    const float* feats  = (const float*)d_in[0];
    const float* coords = (const float*)d_in[1];
    const void*  cids   = d_in[2];
    const void*  pids   = d_in[3];
    float* out = (float*)d_out;
    char* ws = (char*)d_ws;

    // ws layout (bytes), total 12,440,704:
    //   0         double gsum[256*3]       (6144)    } zero
    //   6144      uint   gcnt[256]         (1024)    } zero
    //   7168      uint   gmax[256*3]       (3072)    } zero
    //   10240     uint   vptr[VOXT+1]      (2809860) } zero -> pad 2820160
    //   2820160   uint   gminN[256*3]      (3072)    } zero (negated encodings)
    //   2823232   double params[256*8]     (16384)
    //   2839616   int    coff[257]         (1028 -> pad 2840704)
    //   2840704   u16    vidl[SPAIRS]      (1200000) -> 4040704
    //   4040704   u16    rankl[SPAIRS]     (1200000) -> 5240704
    //   5240704   float  ccoord[3*SPAIRS]  (7200000) -> 12440704
    //             int    spid[SPAIRS]      (2400000) ALIASES ccoord (dead after k_vox)
    double*   gsum   = (double*)(ws + 0);
    uint*     gcnt   = (uint*)(ws + 6144);
    uint*     gmax   = (uint*)(ws + 7168);
    uint*     vptr   = (uint*)(ws + 10240);
    uint*     gminN  = (uint*)(ws + 2820160);
    double*   params = (double*)(ws + 2823232);
    int*      coff   = (int*)(ws + 2839616);
    ushort_t* vidl   = (ushort_t*)(ws + 2840704);
    ushort_t* rankl  = (ushort_t*)(ws + 4040704);
    float*    ccoord = (float*)(ws + 5240704);
    int*      spid   = (int*)(ws + 5240704);     // alias: ccoord dead before k_scatter
    uint*     agg    = (uint*)(out + (size_t)VOXT * 32);

    hipMemsetAsync(ws, 0, 2823232, stream);      // gsum..gminN

    int nb = (SPAIRS + 255) / 256;   // 2344
    k_stats<<<nb, 256, 0, stream>>>(cids, pids, coords, gsum, gcnt, gminN, gmax, ccoord);
    k_params<<<1, 256, 0, stream>>>(gsum, gcnt, gminN, gmax, params, coff);
    k_vox<<<nb, 256, 0, stream>>>(cids, ccoord, params, vidl, rankl, vptr);
    k_scan<<<NC, 256, 0, stream>>>(coff, vptr, agg);
    k_scatter<<<nb, 256, 0, stream>>>(cids, pids, vidl, rankl, vptr, spid);
    k_out<<<NBLK, 256, 0, stream>>>((const float4*)feats, vptr, spid, out, agg);
    k_aggfin<<<(NC * 32) / 256, 256, 0, stream>>>(out);
}

// Round 11
// 97.502 us; speedup vs baseline: 3.0956x; 1.0019x over previous
//
#include <hip/hip_runtime.h>
#include <stdint.h>

typedef unsigned int uint;
typedef unsigned short ushort_t;

#define NPTS 500000
#define NC 256
#define SPAIRS 600000
#define FS 14
#define F3 2744            // 14^3
#define VOXT (NC * F3)     // 702464
#define STRIP 343          // F3/8 voxels per k_out block
#define PCAP 3072          // LDS pid-stage capacity (max pairs/strip ~2.6K avg 293)
#define NBLK (NC * 8)      // k_out grid
#define ZBYTES 2823232     // zeroed ws prefix (gsum..gminN incl. vptr)
#define ZN4 (ZBYTES / 16)  // 176452 float4s

// ---------- helpers ----------
__device__ __forceinline__ uint encF(float f) {
    uint u = __float_as_uint(f);
    return (u & 0x80000000u) ? ~u : (u | 0x80000000u);
}
__device__ __forceinline__ float decF(uint e) {
    uint u = (e & 0x80000000u) ? (e ^ 0x80000000u) : ~e;
    return __uint_as_float(u);
}
// ids may arrive as int32 (jax x64 off) or int64. Sorted cids: mid values ~128,
// so for int64 the odd int32 words (high) are 0; for int32 they're nonzero.
__device__ __forceinline__ uint detect64(const void* cids) {
    const int* p = (const int*)cids;
    int z = 0;
    #pragma unroll
    for (int k = 0; k < 5; ++k) z += (p[300001 + 2 * k] == 0) ? 1 : 0;
    return (z >= 3) ? 1u : 0u;
}
__device__ __forceinline__ int loadId(const void* p, int i, uint is64) {
    return is64 ? (int)((const long long*)p)[i] : ((const int*)p)[i];
}

// ---------- kernel 0: fast ws zeroing (replaces 51us rocclr fillBuffer) ----------
__global__ __launch_bounds__(256) void k_zero(float4* __restrict__ p) {
    int i = blockIdx.x * 256 + threadIdx.x;
    if (i < ZN4) p[i] = make_float4(0.f, 0.f, 0.f, 0.f);
}

// ---------- kernel 1: per-cluster count/sum(f64)/min/max + cache gathered coords ----------
// min stored as NEGATED monotonic encodings (atomicMax, 0-init) -> no 0xFF memset.
__global__ __launch_bounds__(256) void k_stats(const void* cids, const void* pids,
        const float* __restrict__ coords,
        double* gsum, uint* gcnt, uint* gminN, uint* gmax, float* __restrict__ ccoord) {
    __shared__ double sSum[NC][3];
    __shared__ uint   sCnt[NC];
    __shared__ uint   sMinN[NC][3];
    __shared__ uint   sMax[NC][3];
    int tid = threadIdx.x;
    for (int c = tid; c < NC; c += 256) {
        sCnt[c] = 0u;
        for (int d = 0; d < 3; ++d) { sSum[c][d] = 0.0; sMinN[c][d] = 0u; sMax[c][d] = 0u; }
    }
    __syncthreads();
    uint is64 = detect64(cids);
    int s = blockIdx.x * 256 + tid;
    bool valid = s < SPAIRS;
    int sc = valid ? s : SPAIRS - 1;
    int cid = loadId(cids, sc, is64);
    int pid = loadId(pids, sc, is64);
    float x = coords[3 * pid + 0];
    float y = coords[3 * pid + 1];
    float z = coords[3 * pid + 2];
    if (valid) {               // cache gathered coords contiguously for k_vox
        ccoord[3 * s + 0] = x;
        ccoord[3 * s + 1] = y;
        ccoord[3 * s + 2] = z;
    }
    int lane = tid & 63;
    int cid0 = __shfl(cid, 0, 64), cid63 = __shfl(cid, 63, 64);
    if (cid0 == cid63) {
        uint nval = (uint)__popcll(__ballot(valid));
        double dx = valid ? (double)x : 0.0;
        double dy = valid ? (double)y : 0.0;
        double dz = valid ? (double)z : 0.0;
        float mnx = valid ? x : INFINITY,  mny = valid ? y : INFINITY,  mnz = valid ? z : INFINITY;
        float mxx = valid ? x : -INFINITY, mxy = valid ? y : -INFINITY, mxz = valid ? z : -INFINITY;
        #pragma unroll
        for (int st = 1; st < 64; st <<= 1) {
            dx += __shfl_xor(dx, st, 64);
            dy += __shfl_xor(dy, st, 64);
            dz += __shfl_xor(dz, st, 64);
            mnx = fminf(mnx, __shfl_xor(mnx, st, 64));
            mny = fminf(mny, __shfl_xor(mny, st, 64));
            mnz = fminf(mnz, __shfl_xor(mnz, st, 64));
            mxx = fmaxf(mxx, __shfl_xor(mxx, st, 64));
            mxy = fmaxf(mxy, __shfl_xor(mxy, st, 64));
            mxz = fmaxf(mxz, __shfl_xor(mxz, st, 64));
        }
        if (lane == 0 && nval) {
            atomicAdd(&sCnt[cid0], nval);
            unsafeAtomicAdd(&sSum[cid0][0], dx);
            unsafeAtomicAdd(&sSum[cid0][1], dy);
            unsafeAtomicAdd(&sSum[cid0][2], dz);
            atomicMax(&sMinN[cid0][0], ~encF(mnx)); atomicMax(&sMinN[cid0][1], ~encF(mny)); atomicMax(&sMinN[cid0][2], ~encF(mnz));
            atomicMax(&sMax[cid0][0], encF(mxx));   atomicMax(&sMax[cid0][1], encF(mxy));   atomicMax(&sMax[cid0][2], encF(mxz));
        }
    } else if (valid) {
        atomicAdd(&sCnt[cid], 1u);
        unsafeAtomicAdd(&sSum[cid][0], (double)x);
        unsafeAtomicAdd(&sSum[cid][1], (double)y);
        unsafeAtomicAdd(&sSum[cid][2], (double)z);
        atomicMax(&sMinN[cid][0], ~encF(x)); atomicMax(&sMinN[cid][1], ~encF(y)); atomicMax(&sMinN[cid][2], ~encF(z));
        atomicMax(&sMax[cid][0], encF(x));   atomicMax(&sMax[cid][1], encF(y));   atomicMax(&sMax[cid][2], encF(z));
    }
    __syncthreads();
    for (int c = tid; c < NC; c += 256) {
        if (sCnt[c]) {
            atomicAdd(&gcnt[c], sCnt[c]);
            for (int d = 0; d < 3; ++d) {
                unsafeAtomicAdd(&gsum[c * 3 + d], sSum[c][d]);
                atomicMax(&gminN[c * 3 + d], sMinN[c][d]);
                atomicMax(&gmax[c * 3 + d], sMax[c][d]);
            }
        }
    }
}

// ---------- kernel 2: per-cluster mean/scale/offset (double) + parallel prefix for coff ----------
__global__ void k_params(const double* gsum, const uint* gcnt, const uint* gminN,
                         const uint* gmax, double* params, int* coff) {
    __shared__ uint wsum[4];
    int c = threadIdx.x;                 // exactly 256 threads
    uint n = gcnt[c];
    double mean[3] = {0, 0, 0}, off[3] = {0, 0, 0}, scale = 50.0;
    if (n) {
        double dn = (double)n;
        double r = 0.0, mn[3];
        for (int d = 0; d < 3; ++d) {
            mean[d] = gsum[c * 3 + d] / dn;
            mn[d] = (double)decF(~gminN[c * 3 + d]) - mean[d];
            double mx = (double)decF(gmax[c * 3 + d]) - mean[d];
            double ext = (mx - mn[d]) / (double)FS;
            r = fmax(r, ext);
        }
        double sr = 1.0 / r - 0.01;      // r==0 -> inf -> clamp to 50
        scale = fmin(sr, 50.0);
        for (int d = 0; d < 3; ++d) off[d] = -(mn[d] * scale);
    }
    params[c * 8 + 0] = mean[0]; params[c * 8 + 1] = mean[1]; params[c * 8 + 2] = mean[2];
    params[c * 8 + 3] = scale;
    params[c * 8 + 4] = off[0];  params[c * 8 + 5] = off[1];  params[c * 8 + 6] = off[2];
    params[c * 8 + 7] = 0.0;

    uint incl = n;
    #pragma unroll
    for (int d = 1; d < 64; d <<= 1) {
        uint y = __shfl_up(incl, d, 64);
        if ((c & 63) >= d) incl += y;
    }
    int w = c >> 6;
    if ((c & 63) == 63) wsum[w] = incl;
    __syncthreads();
    uint woff = 0;
    #pragma unroll
    for (int i = 0; i < 4; ++i) if (i < w) woff += wsum[i];
    coff[c] = (int)(incl - n + woff);
    if (c == 255) coff[NC] = (int)(incl + woff);
}

// ---------- kernel 3: voxel id + rank + per-voxel count (fully coalesced reads) ----------
__global__ __launch_bounds__(256) void k_vox(const void* cids,
        const float* __restrict__ ccoord, const double* __restrict__ params,
        ushort_t* vidl, ushort_t* rankl, uint* vptr) {
    int s = blockIdx.x * blockDim.x + threadIdx.x;
    if (s >= SPAIRS) return;
    uint is64 = detect64(cids);
    int cid = loadId(cids, s, is64);
    const double* P = params + cid * 8;
    float cx = ccoord[3 * s + 0];
    float cy = ccoord[3 * s + 1];
    float cz = ccoord[3 * s + 2];
    double vx = ((double)cx - P[0]) * P[3] + P[4];
    double vy = ((double)cy - P[1]) * P[3] + P[5];
    double vz = ((double)cz - P[2]) * P[3] + P[6];
    int ix = (int)floor(vx); ix = ix < 0 ? 0 : (ix > FS - 1 ? FS - 1 : ix);
    int iy = (int)floor(vy); iy = iy < 0 ? 0 : (iy > FS - 1 ? FS - 1 : iy);
    int iz = (int)floor(vz); iz = iz < 0 ? 0 : (iz > FS - 1 ? FS - 1 : iz);
    int v = (ix * FS + iy) * FS + iz;
    vidl[s] = (ushort_t)v;
    uint r = atomicAdd(&vptr[cid * F3 + v], 1u);   // rank within voxel
    rankl[s] = (ushort_t)r;
}

// ---------- kernel 4: per-cluster exclusive scan of vptr (+coff base) + sentinel + agg zero ----------
__global__ __launch_bounds__(256) void k_scan(const int* coff, uint* vptr, uint* agg) {
    __shared__ uint wsum[4];
    int c = blockIdx.x, t = threadIdx.x;
    uint* base = vptr + c * F3;
    int b0 = t * 11;                 // 11*256 = 2816 >= F3
    uint v[11];
    uint s = 0;
    #pragma unroll
    for (int i = 0; i < 11; ++i) {
        int idx = b0 + i;
        uint x = (idx < F3) ? base[idx] : 0u;
        v[i] = s;
        s += x;
    }
    uint run = s;
    #pragma unroll
    for (int d = 1; d < 64; d <<= 1) {
        uint y = __shfl_up(run, d, 64);
        if ((t & 63) >= d) run += y;
    }
    int w = t >> 6;
    if ((t & 63) == 63) wsum[w] = run;
    __syncthreads();
    uint woff = 0;
    #pragma unroll
    for (int i = 0; i < 4; ++i) if (i < w) woff += wsum[i];
    uint excl = run - s + woff + (uint)coff[c];
    #pragma unroll
    for (int i = 0; i < 11; ++i) {
        int idx = b0 + i;
        if (idx < F3) base[idx] = excl + v[i];   // exclusive start per voxel
    }
    if (c == 255 && t == 0) vptr[VOXT] = (uint)coff[NC];   // sentinel
    if (t < 32) agg[c * 32 + t] = 0u;                      // agg-enc zero
}

// ---------- kernel 5: deterministic scatter: spid = pair pids sorted by (cluster,voxel) ----------
__global__ __launch_bounds__(256) void k_scatter(const void* cids, const void* pids,
        const ushort_t* vidl, const ushort_t* rankl, const uint* vptr, int* spid) {
    int s = blockIdx.x * blockDim.x + threadIdx.x;
    if (s >= SPAIRS) return;
    uint is64 = detect64(cids);
    int cid = loadId(cids, s, is64);
    int pid = loadId(pids, s, is64);
    int vid = cid * F3 + (int)vidl[s];
    uint pos = vptr[vid] + (uint)rankl[s];
    spid[pos] = pid;
}

// ---------- kernel 6: float4 channel-group voxel mean + agg max ----------
// Thread owns (voxel, 4-channel group): all hot loads/stores are float4 with
// 32-bit offsets. 2 voxels/thread/iter -> 4 independent float4 loads in flight.
// NO device-scope fences here (R9 lesson: threadfence in a 2048-block grid
// forces serialized per-XCD L2 writebacks -> ~200us of stall).
__global__ __launch_bounds__(256) void k_out(const float4* __restrict__ feats4,
        const uint* __restrict__ vptr, const int* __restrict__ spid,
        float* __restrict__ out, uint* __restrict__ agg) {
    __shared__ uint  sVptr[344];
    __shared__ int   sPid[PCAP];
    __shared__ float sMxA[32][8][4];
    int b = blockIdx.x;
    int xcd = b & 7, r = b >> 3;
    int c = xcd * 32 + (r >> 3);     // cluster (XCD-swizzled)
    int p = r & 7;                   // eighth
    int t = threadIdx.x;
    int vid0 = c * F3 + p * STRIP;

    sVptr[t] = vptr[vid0 + t];
    if (t < 88) sVptr[256 + t] = vptr[vid0 + 256 + t];
    if (t == 0) sPid[0] = 0;                     // np==0 safety
    __syncthreads();
    uint S0 = sVptr[0], S1 = sVptr[343];
    int np = (int)(S1 - S0);
    bool fits = np <= PCAP;
    if (fits) for (int i = t; i < np; i += 256) sPid[i] = spid[S0 + i];
    __syncthreads();

    int vox = t >> 3;                // voxel slot 0..31
    int chg = t & 7;                 // float4 channel group
    float4 mx = make_float4(-INFINITY, -INFINITY, -INFINITY, -INFINITY);

    #pragma unroll 2
    for (int jb = 0; jb < 6; ++jb) {
        int v0 = vox + 64 * jb, v1 = v0 + 32;    // 12 strided voxels/thread total
        bool ok0 = v0 < STRIP, ok1 = v1 < STRIP;
        int vc0 = ok0 ? v0 : 342, vc1 = ok1 ? v1 : 342;
        uint s00 = sVptr[vc0]; uint cn0 = ok0 ? (sVptr[vc0 + 1] - s00) : 0u;
        uint s10 = sVptr[vc1]; uint cn1 = ok1 ? (sVptr[vc1 + 1] - s10) : 0u;
        uint i00 = s00 - S0, i10 = s10 - S0;
        uint a0 = (cn0 >= 1) ? i00 : 0u;  uint b0 = (cn0 >= 2) ? (i00 + 1) : a0;
        uint a1 = (cn1 >= 1) ? i10 : 0u;  uint b1 = (cn1 >= 2) ? (i10 + 1) : a1;
        int p00 = fits ? sPid[a0] : spid[S0 + a0];
        int p01 = fits ? sPid[b0] : spid[S0 + b0];
        int p10 = fits ? sPid[a1] : spid[S0 + a1];
        int p11 = fits ? sPid[b1] : spid[S0 + b1];
        float4 f00 = feats4[(uint)p00 * 8u + (uint)chg];   // 4 independent 16B loads
        float4 f01 = feats4[(uint)p01 * 8u + (uint)chg];
        float4 f10 = feats4[(uint)p10 * 8u + (uint)chg];
        float4 f11 = feats4[(uint)p11 * 8u + (uint)chg];

        float4 acc0, acc1;
        acc0.x = ((cn0 >= 1) ? f00.x : 0.f) + ((cn0 >= 2) ? f01.x : 0.f);
        acc0.y = ((cn0 >= 1) ? f00.y : 0.f) + ((cn0 >= 2) ? f01.y : 0.f);
        acc0.z = ((cn0 >= 1) ? f00.z : 0.f) + ((cn0 >= 2) ? f01.z : 0.f);
        acc0.w = ((cn0 >= 1) ? f00.w : 0.f) + ((cn0 >= 2) ? f01.w : 0.f);
        acc1.x = ((cn1 >= 1) ? f10.x : 0.f) + ((cn1 >= 2) ? f11.x : 0.f);
        acc1.y = ((cn1 >= 1) ? f10.y : 0.f) + ((cn1 >= 2) ? f11.y : 0.f);
        acc1.z = ((cn1 >= 1) ? f10.z : 0.f) + ((cn1 >= 2) ? f11.z : 0.f);
        acc1.w = ((cn1 >= 1) ? f10.w : 0.f) + ((cn1 >= 2) ? f11.w : 0.f);
        if (cn0 >= 1) { mx.x = fmaxf(mx.x, f00.x); mx.y = fmaxf(mx.y, f00.y); mx.z = fmaxf(mx.z, f00.z); mx.w = fmaxf(mx.w, f00.w); }
        if (cn0 >= 2) { mx.x = fmaxf(mx.x, f01.x); mx.y = fmaxf(mx.y, f01.y); mx.z = fmaxf(mx.z, f01.z); mx.w = fmaxf(mx.w, f01.w); }
        if (cn1 >= 1) { mx.x = fmaxf(mx.x, f10.x); mx.y = fmaxf(mx.y, f10.y); mx.z = fmaxf(mx.z, f10.z); mx.w = fmaxf(mx.w, f10.w); }
        if (cn1 >= 2) { mx.x = fmaxf(mx.x, f11.x); mx.y = fmaxf(mx.y, f11.y); mx.z = fmaxf(mx.z, f11.z); mx.w = fmaxf(mx.w, f11.w); }

        if (cn0 > 2) {                         // rare tails (~5.5% of voxels)
            for (uint q = 2; q < cn0; ++q) {
                int pq = fits ? sPid[i00 + q] : spid[S0 + i00 + q];
                float4 fq = feats4[(uint)pq * 8u + (uint)chg];
                acc0.x += fq.x; acc0.y += fq.y; acc0.z += fq.z; acc0.w += fq.w;
                mx.x = fmaxf(mx.x, fq.x); mx.y = fmaxf(mx.y, fq.y); mx.z = fmaxf(mx.z, fq.z); mx.w = fmaxf(mx.w, fq.w);
            }
        }
        if (cn1 > 2) {
            for (uint q = 2; q < cn1; ++q) {
                int pq = fits ? sPid[i10 + q] : spid[S0 + i10 + q];
                float4 fq = feats4[(uint)pq * 8u + (uint)chg];
                acc1.x += fq.x; acc1.y += fq.y; acc1.z += fq.z; acc1.w += fq.w;
                mx.x = fmaxf(mx.x, fq.x); mx.y = fmaxf(mx.y, fq.y); mx.z = fmaxf(mx.z, fq.z); mx.w = fmaxf(mx.w, fq.w);
            }
        }
        if (ok0) {
            float inv = __builtin_amdgcn_rcpf(cn0 ? (float)cn0 : 1.f);
            float4 rr; rr.x = acc0.x * inv; rr.y = acc0.y * inv; rr.z = acc0.z * inv; rr.w = acc0.w * inv;
            *(float4*)(out + (uint)(vid0 + v0) * 32u + (uint)chg * 4u) = rr;
        }
        if (ok1) {
            float inv = __builtin_amdgcn_rcpf(cn1 ? (float)cn1 : 1.f);
            float4 rr; rr.x = acc1.x * inv; rr.y = acc1.y * inv; rr.z = acc1.z * inv; rr.w = acc1.w * inv;
            *(float4*)(out + (uint)(vid0 + v1) * 32u + (uint)chg * 4u) = rr;
        }
    }

    sMxA[vox][chg][0] = mx.x; sMxA[vox][chg][1] = mx.y;
    sMxA[vox][chg][2] = mx.z; sMxA[vox][chg][3] = mx.w;
    __syncthreads();
    if (t < 32) {                    // t = channel; chg = t>>2, elem = t&3
        float m = -INFINITY;
        #pragma unroll
        for (int v = 0; v < 32; ++v) m = fmaxf(m, sMxA[v][t >> 2][t & 3]);
        if (m != -INFINITY) atomicMax(&agg[c * 32 + t], encF(m));
    }
}

// ---------- kernel 7: agg finalize (decode; untouched/neginf -> 0) ----------
__global__ void k_aggfin(float* outbase) {
    int i = blockIdx.x * blockDim.x + threadIdx.x;     // < NC*32 exactly
    uint* a = (uint*)(outbase + (size_t)VOXT * 32);
    uint e = a[i];
    float f = decF(e);
    if (e == 0u || f == -INFINITY) f = 0.0f;
    ((float*)a)[i] = f;
}

extern "C" void kernel_launch(void* const* d_in, const int* in_sizes, int n_in,
                              void* d_out, int out_size, void* d_ws, size_t ws_size,
                              hipStream_t stream) {
    const float* feats  = (const float*)d_in[0];
    const float* coords = (const float*)d_in[1];
    const void*  cids   = d_in[2];
    const void*  pids   = d_in[3];
    float* out = (float*)d_out;
    char* ws = (char*)d_ws;

    // ws layout (bytes), total 12,440,704:
    //   0         double gsum[256*3]       (6144)    } zero (k_zero)
    //   6144      uint   gcnt[256]         (1024)    } zero
    //   7168      uint   gmax[256*3]       (3072)    } zero
    //   10240     uint   vptr[VOXT+1]      (2809860) } zero -> pad 2820160
    //   2820160   uint   gminN[256*3]      (3072)    } zero (negated encodings)
    //   2823232   double params[256*8]     (16384)
    //   2839616   int    coff[257]         (1028 -> pad 2840704)
    //   2840704   u16    vidl[SPAIRS]      (1200000) -> 4040704
    //   4040704   u16    rankl[SPAIRS]     (1200000) -> 5240704
    //   5240704   float  ccoord[3*SPAIRS]  (7200000) -> 12440704
    //             int    spid[SPAIRS]      (2400000) ALIASES ccoord (dead after k_vox)
    double*   gsum   = (double*)(ws + 0);
    uint*     gcnt   = (uint*)(ws + 6144);
    uint*     gmax   = (uint*)(ws + 7168);
    uint*     vptr   = (uint*)(ws + 10240);
    uint*     gminN  = (uint*)(ws + 2820160);
    double*   params = (double*)(ws + 2823232);
    int*      coff   = (int*)(ws + 2839616);
    ushort_t* vidl   = (ushort_t*)(ws + 2840704);
    ushort_t* rankl  = (ushort_t*)(ws + 4040704);
    float*    ccoord = (float*)(ws + 5240704);
    int*      spid   = (int*)(ws + 5240704);     // alias: ccoord dead before k_scatter
    uint*     agg    = (uint*)(out + (size_t)VOXT * 32);

    int nb = (SPAIRS + 255) / 256;   // 2344
    k_zero<<<(ZN4 + 255) / 256, 256, 0, stream>>>((float4*)ws);
    k_stats<<<nb, 256, 0, stream>>>(cids, pids, coords, gsum, gcnt, gminN, gmax, ccoord);
    k_params<<<1, 256, 0, stream>>>(gsum, gcnt, gminN, gmax, params, coff);
    k_vox<<<nb, 256, 0, stream>>>(cids, ccoord, params, vidl, rankl, vptr);
    k_scan<<<NC, 256, 0, stream>>>(coff, vptr, agg);
    k_scatter<<<nb, 256, 0, stream>>>(cids, pids, vidl, rankl, vptr, spid);
    k_out<<<NBLK, 256, 0, stream>>>((const float4*)feats, vptr, spid, out, agg);
    k_aggfin<<<(NC * 32) / 256, 256, 0, stream>>>(out);
}

// Round 12
// 93.866 us; speedup vs baseline: 3.2155x; 1.0387x over previous
//
#include <hip/hip_runtime.h>
#include <stdint.h>

typedef unsigned int uint;
typedef unsigned short ushort_t;

#define NPTS 500000
#define NC 256
#define SPAIRS 600000
#define FS 14
#define F3 2744            // 14^3
#define VOXT (NC * F3)     // 702464
#define STRIP 343          // F3/8 voxels per k_out block
#define PCAP 3072          // LDS pid-stage capacity (max pairs/strip ~380)
#define NBLK (NC * 8)      // k_out grid
#define ZN4 832            // 13312 B stats region / 16

// ---------- helpers ----------
__device__ __forceinline__ uint encF(float f) {
    uint u = __float_as_uint(f);
    return (u & 0x80000000u) ? ~u : (u | 0x80000000u);
}
__device__ __forceinline__ float decF(uint e) {
    uint u = (e & 0x80000000u) ? (e ^ 0x80000000u) : ~e;
    return __uint_as_float(u);
}
// ids may arrive as int32 (jax x64 off) or int64. Sorted cids: mid values ~128,
// so for int64 the odd int32 words (high) are 0; for int32 they're nonzero.
__device__ __forceinline__ uint detect64(const void* cids) {
    const int* p = (const int*)cids;
    int z = 0;
    #pragma unroll
    for (int k = 0; k < 5; ++k) z += (p[300001 + 2 * k] == 0) ? 1 : 0;
    return (z >= 3) ? 1u : 0u;
}
__device__ __forceinline__ int loadId(const void* p, int i, uint is64) {
    return is64 ? (int)((const long long*)p)[i] : ((const int*)p)[i];
}

// ---------- kernel 0: zero the 13 KB stats region (gsum/gcnt/gmax/gminN) ----------
__global__ __launch_bounds__(256) void k_zero(float4* __restrict__ p) {
    int i = blockIdx.x * 256 + threadIdx.x;
    if (i < ZN4) p[i] = make_float4(0.f, 0.f, 0.f, 0.f);
}

// ---------- kernel 1: per-cluster count/sum(f64)/min/max + ccoord cache + vptr zero ----------
// min stored as NEGATED monotonic encodings (atomicMax, 0-init).
// Each block also zeroes its 300-uint slice of vptr (vptr unused until k_vox).
__global__ __launch_bounds__(256) void k_stats(const void* cids, const void* pids,
        const float* __restrict__ coords,
        double* gsum, uint* gcnt, uint* gminN, uint* gmax, float* __restrict__ ccoord,
        uint* __restrict__ vptr) {
    __shared__ double sSum[NC][3];
    __shared__ uint   sCnt[NC];
    __shared__ uint   sMinN[NC][3];
    __shared__ uint   sMax[NC][3];
    int tid = threadIdx.x;
    // zero vptr slice: 75 uint4 per block (2344*75 = 175800 >= 175617 needed)
    {
        int zb = blockIdx.x * 75 + tid;              // uint4 index
        if (tid < 75) {
            if (zb < (VOXT / 4)) ((uint4*)vptr)[zb] = make_uint4(0u, 0u, 0u, 0u);
            else if (zb == (VOXT / 4)) vptr[VOXT] = 0u;   // sentinel word (VOXT%4==0)
        }
    }
    for (int c = tid; c < NC; c += 256) {
        sCnt[c] = 0u;
        for (int d = 0; d < 3; ++d) { sSum[c][d] = 0.0; sMinN[c][d] = 0u; sMax[c][d] = 0u; }
    }
    __syncthreads();
    uint is64 = detect64(cids);
    int s = blockIdx.x * 256 + tid;
    bool valid = s < SPAIRS;
    int sc = valid ? s : SPAIRS - 1;
    int cid = loadId(cids, sc, is64);
    int pid = loadId(pids, sc, is64);
    float x = coords[3 * pid + 0];
    float y = coords[3 * pid + 1];
    float z = coords[3 * pid + 2];
    if (valid) {               // cache gathered coords contiguously for k_vox
        ccoord[3 * s + 0] = x;
        ccoord[3 * s + 1] = y;
        ccoord[3 * s + 2] = z;
    }
    int lane = tid & 63;
    int cid0 = __shfl(cid, 0, 64), cid63 = __shfl(cid, 63, 64);
    if (cid0 == cid63) {
        uint nval = (uint)__popcll(__ballot(valid));
        double dx = valid ? (double)x : 0.0;
        double dy = valid ? (double)y : 0.0;
        double dz = valid ? (double)z : 0.0;
        float mnx = valid ? x : INFINITY,  mny = valid ? y : INFINITY,  mnz = valid ? z : INFINITY;
        float mxx = valid ? x : -INFINITY, mxy = valid ? y : -INFINITY, mxz = valid ? z : -INFINITY;
        #pragma unroll
        for (int st = 1; st < 64; st <<= 1) {
            dx += __shfl_xor(dx, st, 64);
            dy += __shfl_xor(dy, st, 64);
            dz += __shfl_xor(dz, st, 64);
            mnx = fminf(mnx, __shfl_xor(mnx, st, 64));
            mny = fminf(mny, __shfl_xor(mny, st, 64));
            mnz = fminf(mnz, __shfl_xor(mnz, st, 64));
            mxx = fmaxf(mxx, __shfl_xor(mxx, st, 64));
            mxy = fmaxf(mxy, __shfl_xor(mxy, st, 64));
            mxz = fmaxf(mxz, __shfl_xor(mxz, st, 64));
        }
        if (lane == 0 && nval) {
            atomicAdd(&sCnt[cid0], nval);
            unsafeAtomicAdd(&sSum[cid0][0], dx);
            unsafeAtomicAdd(&sSum[cid0][1], dy);
            unsafeAtomicAdd(&sSum[cid0][2], dz);
            atomicMax(&sMinN[cid0][0], ~encF(mnx)); atomicMax(&sMinN[cid0][1], ~encF(mny)); atomicMax(&sMinN[cid0][2], ~encF(mnz));
            atomicMax(&sMax[cid0][0], encF(mxx));   atomicMax(&sMax[cid0][1], encF(mxy));   atomicMax(&sMax[cid0][2], encF(mxz));
        }
    } else if (valid) {
        atomicAdd(&sCnt[cid], 1u);
        unsafeAtomicAdd(&sSum[cid][0], (double)x);
        unsafeAtomicAdd(&sSum[cid][1], (double)y);
        unsafeAtomicAdd(&sSum[cid][2], (double)z);
        atomicMax(&sMinN[cid][0], ~encF(x)); atomicMax(&sMinN[cid][1], ~encF(y)); atomicMax(&sMinN[cid][2], ~encF(z));
        atomicMax(&sMax[cid][0], encF(x));   atomicMax(&sMax[cid][1], encF(y));   atomicMax(&sMax[cid][2], encF(z));
    }
    __syncthreads();
    for (int c = tid; c < NC; c += 256) {
        if (sCnt[c]) {
            atomicAdd(&gcnt[c], sCnt[c]);
            for (int d = 0; d < 3; ++d) {
                unsafeAtomicAdd(&gsum[c * 3 + d], sSum[c][d]);
                atomicMax(&gminN[c * 3 + d], sMinN[c][d]);
                atomicMax(&gmax[c * 3 + d], sMax[c][d]);
            }
        }
    }
}

// ---------- kernel 2: per-cluster mean/scale/offset (double) + parallel prefix for coff ----------
__global__ void k_params(const double* gsum, const uint* gcnt, const uint* gminN,
                         const uint* gmax, double* params, int* coff) {
    __shared__ uint wsum[4];
    int c = threadIdx.x;                 // exactly 256 threads
    uint n = gcnt[c];
    double mean[3] = {0, 0, 0}, off[3] = {0, 0, 0}, scale = 50.0;
    if (n) {
        double dn = (double)n;
        double r = 0.0, mn[3];
        for (int d = 0; d < 3; ++d) {
            mean[d] = gsum[c * 3 + d] / dn;
            mn[d] = (double)decF(~gminN[c * 3 + d]) - mean[d];
            double mx = (double)decF(gmax[c * 3 + d]) - mean[d];
            double ext = (mx - mn[d]) / (double)FS;
            r = fmax(r, ext);
        }
        double sr = 1.0 / r - 0.01;      // r==0 -> inf -> clamp to 50
        scale = fmin(sr, 50.0);
        for (int d = 0; d < 3; ++d) off[d] = -(mn[d] * scale);
    }
    params[c * 8 + 0] = mean[0]; params[c * 8 + 1] = mean[1]; params[c * 8 + 2] = mean[2];
    params[c * 8 + 3] = scale;
    params[c * 8 + 4] = off[0];  params[c * 8 + 5] = off[1];  params[c * 8 + 6] = off[2];
    params[c * 8 + 7] = 0.0;

    uint incl = n;
    #pragma unroll
    for (int d = 1; d < 64; d <<= 1) {
        uint y = __shfl_up(incl, d, 64);
        if ((c & 63) >= d) incl += y;
    }
    int w = c >> 6;
    if ((c & 63) == 63) wsum[w] = incl;
    __syncthreads();
    uint woff = 0;
    #pragma unroll
    for (int i = 0; i < 4; ++i) if (i < w) woff += wsum[i];
    coff[c] = (int)(incl - n + woff);
    if (c == 255) coff[NC] = (int)(incl + woff);
}

// ---------- kernel 3: voxel id + rank -> packed vrank, per-voxel count ----------
__global__ __launch_bounds__(256) void k_vox(const void* cids,
        const float* __restrict__ ccoord, const double* __restrict__ params,
        uint* __restrict__ vrank, uint* vptr) {
    int s = blockIdx.x * blockDim.x + threadIdx.x;
    if (s >= SPAIRS) return;
    uint is64 = detect64(cids);
    int cid = loadId(cids, s, is64);
    const double* P = params + cid * 8;
    float cx = ccoord[3 * s + 0];
    float cy = ccoord[3 * s + 1];
    float cz = ccoord[3 * s + 2];
    double vx = ((double)cx - P[0]) * P[3] + P[4];
    double vy = ((double)cy - P[1]) * P[3] + P[5];
    double vz = ((double)cz - P[2]) * P[3] + P[6];
    int ix = (int)floor(vx); ix = ix < 0 ? 0 : (ix > FS - 1 ? FS - 1 : ix);
    int iy = (int)floor(vy); iy = iy < 0 ? 0 : (iy > FS - 1 ? FS - 1 : iy);
    int iz = (int)floor(vz); iz = iz < 0 ? 0 : (iz > FS - 1 ? FS - 1 : iz);
    int v = (ix * FS + iy) * FS + iz;
    uint r = atomicAdd(&vptr[cid * F3 + v], 1u);   // rank within voxel (< 2^20)
    vrank[s] = (r << 12) | (uint)v;                // v < 2744 < 4096
}

// ---------- kernel 4: fused per-cluster scan + scatter (block = cluster) ----------
// Phase 1: exclusive scan of this cluster's 2744 counts (+coff base); starts kept
// in LDS and written to global vptr once. Phase 2: scatter own pairs using LDS
// starts -> no global vptr re-read, no cids read (cid == blockIdx), no atomics.
__global__ __launch_bounds__(256) void k_scansct(const void* cids, const void* pids,
        const int* coff, const uint* __restrict__ vrank,
        uint* vptr, uint* agg, int* spid) {
    __shared__ uint sStart[F3];      // 10976 B
    __shared__ uint wsum[4];
    int c = blockIdx.x, t = threadIdx.x;
    uint* base = vptr + c * F3;
    int b0 = t * 11;                 // 11*256 = 2816 >= F3
    uint v[11];
    uint s = 0;
    #pragma unroll
    for (int i = 0; i < 11; ++i) {
        int idx = b0 + i;
        uint x = (idx < F3) ? base[idx] : 0u;
        v[i] = s;
        s += x;
    }
    uint run = s;
    #pragma unroll
    for (int d = 1; d < 64; d <<= 1) {
        uint y = __shfl_up(run, d, 64);
        if ((t & 63) >= d) run += y;
    }
    int w = t >> 6;
    if ((t & 63) == 63) wsum[w] = run;
    __syncthreads();
    uint woff = 0;
    #pragma unroll
    for (int i = 0; i < 4; ++i) if (i < w) woff += wsum[i];
    uint excl = run - s + woff + (uint)coff[c];
    #pragma unroll
    for (int i = 0; i < 11; ++i) {
        int idx = b0 + i;
        if (idx < F3) {
            uint sv = excl + v[i];
            base[idx] = sv;          // exclusive start per voxel (global, for k_out)
            sStart[idx] = sv;        // LDS copy for local scatter
        }
    }
    if (c == 255 && t == 0) vptr[VOXT] = (uint)coff[NC];   // sentinel
    if (t < 32) agg[c * 32 + t] = 0u;                      // agg-enc zero
    __syncthreads();

    // phase 2: scatter this cluster's pairs
    uint is64 = detect64(cids);
    int s0 = coff[c], s1 = coff[c + 1];
    for (int q = s0 + t; q < s1; q += 256) {
        int pid = loadId(pids, q, is64);
        uint vr = vrank[q];
        uint pos = sStart[vr & 4095u] + (vr >> 12);
        spid[pos] = pid;
    }
}

// ---------- kernel 5: float4 channel-group voxel mean + agg max ----------
// Thread owns (voxel, 4-channel group): all hot loads/stores are float4 with
// 32-bit offsets. 2 voxels/thread/iter -> 4 independent float4 loads in flight.
// NO device-scope fences (R9 lesson: threadfence in a wide grid -> L2 drain storm).
__global__ __launch_bounds__(256) void k_out(const float4* __restrict__ feats4,
        const uint* __restrict__ vptr, const int* __restrict__ spid,
        float* __restrict__ out, uint* __restrict__ agg) {
    __shared__ uint  sVptr[344];
    __shared__ int   sPid[PCAP];
    __shared__ float sMxA[32][8][4];
    int b = blockIdx.x;
    int xcd = b & 7, r = b >> 3;
    int c = xcd * 32 + (r >> 3);     // cluster (XCD-swizzled)
    int p = r & 7;                   // eighth
    int t = threadIdx.x;
    int vid0 = c * F3 + p * STRIP;

    sVptr[t] = vptr[vid0 + t];
    if (t < 88) sVptr[256 + t] = vptr[vid0 + 256 + t];
    if (t == 0) sPid[0] = 0;                     // np==0 safety
    __syncthreads();
    uint S0 = sVptr[0], S1 = sVptr[343];
    int np = (int)(S1 - S0);
    bool fits = np <= PCAP;
    if (fits) for (int i = t; i < np; i += 256) sPid[i] = spid[S0 + i];
    __syncthreads();

    int vox = t >> 3;                // voxel slot 0..31
    int chg = t & 7;                 // float4 channel group
    float4 mx = make_float4(-INFINITY, -INFINITY, -INFINITY, -INFINITY);

    #pragma unroll 2
    for (int jb = 0; jb < 6; ++jb) {
        int v0 = vox + 64 * jb, v1 = v0 + 32;    // 12 strided voxels/thread total
        bool ok0 = v0 < STRIP, ok1 = v1 < STRIP;
        int vc0 = ok0 ? v0 : 342, vc1 = ok1 ? v1 : 342;
        uint s00 = sVptr[vc0]; uint cn0 = ok0 ? (sVptr[vc0 + 1] - s00) : 0u;
        uint s10 = sVptr[vc1]; uint cn1 = ok1 ? (sVptr[vc1 + 1] - s10) : 0u;
        uint i00 = s00 - S0, i10 = s10 - S0;
        uint a0 = (cn0 >= 1) ? i00 : 0u;  uint b0 = (cn0 >= 2) ? (i00 + 1) : a0;
        uint a1 = (cn1 >= 1) ? i10 : 0u;  uint b1 = (cn1 >= 2) ? (i10 + 1) : a1;
        int p00 = fits ? sPid[a0] : spid[S0 + a0];
        int p01 = fits ? sPid[b0] : spid[S0 + b0];
        int p10 = fits ? sPid[a1] : spid[S0 + a1];
        int p11 = fits ? sPid[b1] : spid[S0 + b1];
        float4 f00 = feats4[(uint)p00 * 8u + (uint)chg];   // 4 independent 16B loads
        float4 f01 = feats4[(uint)p01 * 8u + (uint)chg];
        float4 f10 = feats4[(uint)p10 * 8u + (uint)chg];
        float4 f11 = feats4[(uint)p11 * 8u + (uint)chg];

        float4 acc0, acc1;
        acc0.x = ((cn0 >= 1) ? f00.x : 0.f) + ((cn0 >= 2) ? f01.x : 0.f);
        acc0.y = ((cn0 >= 1) ? f00.y : 0.f) + ((cn0 >= 2) ? f01.y : 0.f);
        acc0.z = ((cn0 >= 1) ? f00.z : 0.f) + ((cn0 >= 2) ? f01.z : 0.f);
        acc0.w = ((cn0 >= 1) ? f00.w : 0.f) + ((cn0 >= 2) ? f01.w : 0.f);
        acc1.x = ((cn1 >= 1) ? f10.x : 0.f) + ((cn1 >= 2) ? f11.x : 0.f);
        acc1.y = ((cn1 >= 1) ? f10.y : 0.f) + ((cn1 >= 2) ? f11.y : 0.f);
        acc1.z = ((cn1 >= 1) ? f10.z : 0.f) + ((cn1 >= 2) ? f11.z : 0.f);
        acc1.w = ((cn1 >= 1) ? f10.w : 0.f) + ((cn1 >= 2) ? f11.w : 0.f);
        if (cn0 >= 1) { mx.x = fmaxf(mx.x, f00.x); mx.y = fmaxf(mx.y, f00.y); mx.z = fmaxf(mx.z, f00.z); mx.w = fmaxf(mx.w, f00.w); }
        if (cn0 >= 2) { mx.x = fmaxf(mx.x, f01.x); mx.y = fmaxf(mx.y, f01.y); mx.z = fmaxf(mx.z, f01.z); mx.w = fmaxf(mx.w, f01.w); }
        if (cn1 >= 1) { mx.x = fmaxf(mx.x, f10.x); mx.y = fmaxf(mx.y, f10.y); mx.z = fmaxf(mx.z, f10.z); mx.w = fmaxf(mx.w, f10.w); }
        if (cn1 >= 2) { mx.x = fmaxf(mx.x, f11.x); mx.y = fmaxf(mx.y, f11.y); mx.z = fmaxf(mx.z, f11.z); mx.w = fmaxf(mx.w, f11.w); }

        if (cn0 > 2) {                         // rare tails (~5.5% of voxels)
            for (uint q = 2; q < cn0; ++q) {
                int pq = fits ? sPid[i00 + q] : spid[S0 + i00 + q];
                float4 fq = feats4[(uint)pq * 8u + (uint)chg];
                acc0.x += fq.x; acc0.y += fq.y; acc0.z += fq.z; acc0.w += fq.w;
                mx.x = fmaxf(mx.x, fq.x); mx.y = fmaxf(mx.y, fq.y); mx.z = fmaxf(mx.z, fq.z); mx.w = fmaxf(mx.w, fq.w);
            }
        }
        if (cn1 > 2) {
            for (uint q = 2; q < cn1; ++q) {
                int pq = fits ? sPid[i10 + q] : spid[S0 + i10 + q];
                float4 fq = feats4[(uint)pq * 8u + (uint)chg];
                acc1.x += fq.x; acc1.y += fq.y; acc1.z += fq.z; acc1.w += fq.w;
                mx.x = fmaxf(mx.x, fq.x); mx.y = fmaxf(mx.y, fq.y); mx.z = fmaxf(mx.z, fq.z); mx.w = fmaxf(mx.w, fq.w);
            }
        }
        if (ok0) {
            float inv = __builtin_amdgcn_rcpf(cn0 ? (float)cn0 : 1.f);
            float4 rr; rr.x = acc0.x * inv; rr.y = acc0.y * inv; rr.z = acc0.z * inv; rr.w = acc0.w * inv;
            *(float4*)(out + (uint)(vid0 + v0) * 32u + (uint)chg * 4u) = rr;
        }
        if (ok1) {
            float inv = __builtin_amdgcn_rcpf(cn1 ? (float)cn1 : 1.f);
            float4 rr; rr.x = acc1.x * inv; rr.y = acc1.y * inv; rr.z = acc1.z * inv; rr.w = acc1.w * inv;
            *(float4*)(out + (uint)(vid0 + v1) * 32u + (uint)chg * 4u) = rr;
        }
    }

    sMxA[vox][chg][0] = mx.x; sMxA[vox][chg][1] = mx.y;
    sMxA[vox][chg][2] = mx.z; sMxA[vox][chg][3] = mx.w;
    __syncthreads();
    if (t < 32) {                    // t = channel; chg = t>>2, elem = t&3
        float m = -INFINITY;
        #pragma unroll
        for (int v = 0; v < 32; ++v) m = fmaxf(m, sMxA[v][t >> 2][t & 3]);
        if (m != -INFINITY) atomicMax(&agg[c * 32 + t], encF(m));
    }
}

// ---------- kernel 6: agg finalize (decode; untouched/neginf -> 0) ----------
__global__ void k_aggfin(float* outbase) {
    int i = blockIdx.x * blockDim.x + threadIdx.x;     // < NC*32 exactly
    uint* a = (uint*)(outbase + (size_t)VOXT * 32);
    uint e = a[i];
    float f = decF(e);
    if (e == 0u || f == -INFINITY) f = 0.0f;
    ((float*)a)[i] = f;
}

extern "C" void kernel_launch(void* const* d_in, const int* in_sizes, int n_in,
                              void* d_out, int out_size, void* d_ws, size_t ws_size,
                              hipStream_t stream) {
    const float* feats  = (const float*)d_in[0];
    const float* coords = (const float*)d_in[1];
    const void*  cids   = d_in[2];
    const void*  pids   = d_in[3];
    float* out = (float*)d_out;
    char* ws = (char*)d_ws;

    // ws layout (bytes), total 12,440,704:
    //   0         double gsum[256*3]       (6144)    } zero (k_zero, 13312 B)
    //   6144      uint   gcnt[256]         (1024)    }
    //   7168      uint   gmax[256*3]       (3072)    }
    //   10240     uint   gminN[256*3]      (3072)    }  (negated encodings)
    //   13312     double params[256*8]     (16384)   -> 29696
    //   29696     int    coff[257]         (1028 -> pad 30784)
    //   30784     uint   vptr[VOXT+1]      (2809860) zeroed inside k_stats -> pad 2840704
    //   2840704   uint   vrank[SPAIRS]     (2400000) -> 5240704   (rank<<12 | vid)
    //   5240704   float  ccoord[3*SPAIRS]  (7200000) -> 12440704
    //             int    spid[SPAIRS]      (2400000) ALIASES ccoord (dead after k_vox)
    double*   gsum   = (double*)(ws + 0);
    uint*     gcnt   = (uint*)(ws + 6144);
    uint*     gmax   = (uint*)(ws + 7168);
    uint*     gminN  = (uint*)(ws + 10240);
    double*   params = (double*)(ws + 13312);
    int*      coff   = (int*)(ws + 29696);
    uint*     vptr   = (uint*)(ws + 30784);
    uint*     vrank  = (uint*)(ws + 2840704);
    float*    ccoord = (float*)(ws + 5240704);
    int*      spid   = (int*)(ws + 5240704);     // alias: ccoord dead before k_scansct
    uint*     agg    = (uint*)(out + (size_t)VOXT * 32);

    int nb = (SPAIRS + 255) / 256;   // 2344
    k_zero<<<4, 256, 0, stream>>>((float4*)ws);
    k_stats<<<nb, 256, 0, stream>>>(cids, pids, coords, gsum, gcnt, gminN, gmax, ccoord, vptr);
    k_params<<<1, 256, 0, stream>>>(gsum, gcnt, gminN, gmax, params, coff);
    k_vox<<<nb, 256, 0, stream>>>(cids, ccoord, params, vrank, vptr);
    k_scansct<<<NC, 256, 0, stream>>>(cids, pids, coff, vrank, vptr, agg, spid);
    k_out<<<NBLK, 256, 0, stream>>>((const float4*)feats, vptr, spid, out, agg);
    k_aggfin<<<(NC * 32) / 256, 256, 0, stream>>>(out);
}

// Round 13
// 52.061 us; speedup vs baseline: 5.7976x; 1.8030x over previous
//
#include <hip/hip_runtime.h>
#include <stdint.h>

typedef unsigned int uint;
typedef unsigned long long ull;

#define NPTS 500000
#define NC 256
#define SPAIRS 600000
#define FS 14
#define F3 2744            // 14^3
#define VOXT (NC * F3)     // 702464
#define STRIP 343          // F3/8 voxels per k_out block
#define PCAP 3072          // LDS pid-stage capacity in k_out (max pairs/cluster ~2.6K)
#define NBLK (NC * 8)      // k_out grid
#define K6 6               // pairs per thread in k_cluster (512*6 = 3072 cap)

// ---------- helpers ----------
__device__ __forceinline__ uint encF(float f) {
    uint u = __float_as_uint(f);
    return (u & 0x80000000u) ? ~u : (u | 0x80000000u);
}
__device__ __forceinline__ float decF(uint e) {
    uint u = (e & 0x80000000u) ? (e ^ 0x80000000u) : ~e;
    return __uint_as_float(u);
}
// ids may arrive as int32 (jax x64 off) or int64. Sorted cids: mid values ~128,
// so for int64 the odd int32 words (high) are 0; for int32 they're nonzero.
__device__ __forceinline__ uint detect64(const void* cids) {
    const int* p = (const int*)cids;
    int z = 0;
    #pragma unroll
    for (int k = 0; k < 5; ++k) z += (p[300001 + 2 * k] == 0) ? 1 : 0;
    return (z >= 3) ? 1u : 0u;
}
__device__ __forceinline__ int loadId(const void* p, int i, uint is64) {
    return is64 ? (int)((const long long*)p)[i] : ((const int*)p)[i];
}

// 64-ary lower_bound over sorted cids using one wave (all 64 lanes participate).
// Answer invariant in [lo, hi]; each round shrinks range ~64x (~4 gather rounds).
__device__ __forceinline__ int lower_bound64(const void* cids, uint is64, int target, int lane) {
    int lo = 0, hi = SPAIRS;
    while (hi - lo > 64) {
        long long span = hi - lo;
        int idx = lo + (int)((span * lane) >> 6);          // lane 0 samples lo
        int v = loadId(cids, idx, is64);
        ull m = __ballot(v < target);                      // prefix mask (sorted)
        int cnt = __popcll(m);
        if (cnt == 0) { hi = lo; break; }                  // cids[lo] >= target
        int nlo = lo + (int)((span * (ull)(cnt - 1)) >> 6) + 1;
        int nhi = (cnt == 64) ? hi : (lo + (int)((span * (ull)cnt) >> 6));
        lo = nlo; hi = nhi;
    }
    if (hi > lo) {
        int idx = min(lo + lane, SPAIRS - 1);
        int v = (lo + lane < hi) ? loadId(cids, idx, is64) : 0x7fffffff;
        ull m = __ballot((lo + lane < hi) && (v < target));
        lo += __popcll(m);
    }
    return lo;
}

// ---------- kernel 1: per-cluster fused stats+params+voxelize+scan+scatter ----------
// Block = cluster. Replaces k_zero/k_stats/k_params/k_vox/k_scansct: no global
// histograms, no memsets, no ccoord/vrank intermediates. coff[c] == lower_bound
// (cids sorted), params block-local in f64, voxel counts+scan+scatter via LDS.
__global__ __launch_bounds__(512) void k_cluster(const void* cids, const void* pids,
        const float* __restrict__ coords,
        uint* __restrict__ vptr, int* __restrict__ spid, uint* __restrict__ agg) {
    __shared__ uint   sCnt[F3];        // voxel counts -> local starts (in place)
    __shared__ uint   wsum[8];
    __shared__ double sRedD[8][3];
    __shared__ float  sRedF[8][6];
    __shared__ double sPar[8];         // mean x3, scale, off x3
    __shared__ int    sBound[2];

    int c = blockIdx.x, t = threadIdx.x;
    int lane = t & 63, wave = t >> 6;
    uint is64 = detect64(cids);

    for (int i = t; i < F3; i += 512) sCnt[i] = 0u;
    if (wave < 2) {
        int r = lower_bound64(cids, is64, c + wave, lane);
        if (lane == 0) sBound[wave] = r;
    }
    __syncthreads();
    int s0 = sBound[0], s1 = sBound[1];
    int n = s1 - s0;

    // ---- loop 1: load own pairs (coalesced pids, gathered coords), accumulate ----
    int   pidR[K6];
    float cxR[K6], cyR[K6], czR[K6];
    double dx = 0.0, dy = 0.0, dz = 0.0;
    float mnx = INFINITY, mny = INFINITY, mnz = INFINITY;
    float mxx = -INFINITY, mxy = -INFINITY, mxz = -INFINITY;
    #pragma unroll
    for (int k = 0; k < K6; ++k) {
        int q = s0 + k * 512 + t;
        bool ok = q < s1;
        int pid = ok ? loadId(pids, q, is64) : 0;
        pidR[k] = pid;
        float x = coords[3 * pid + 0];
        float y = coords[3 * pid + 1];
        float z = coords[3 * pid + 2];
        cxR[k] = x; cyR[k] = y; czR[k] = z;
        if (ok) {
            dx += (double)x; dy += (double)y; dz += (double)z;
            mnx = fminf(mnx, x); mny = fminf(mny, y); mnz = fminf(mnz, z);
            mxx = fmaxf(mxx, x); mxy = fmaxf(mxy, y); mxz = fmaxf(mxz, z);
        }
    }
    #pragma unroll
    for (int st = 1; st < 64; st <<= 1) {
        dx += __shfl_xor(dx, st, 64);
        dy += __shfl_xor(dy, st, 64);
        dz += __shfl_xor(dz, st, 64);
        mnx = fminf(mnx, __shfl_xor(mnx, st, 64));
        mny = fminf(mny, __shfl_xor(mny, st, 64));
        mnz = fminf(mnz, __shfl_xor(mnz, st, 64));
        mxx = fmaxf(mxx, __shfl_xor(mxx, st, 64));
        mxy = fmaxf(mxy, __shfl_xor(mxy, st, 64));
        mxz = fmaxf(mxz, __shfl_xor(mxz, st, 64));
    }
    if (lane == 0) {
        sRedD[wave][0] = dx; sRedD[wave][1] = dy; sRedD[wave][2] = dz;
        sRedF[wave][0] = mnx; sRedF[wave][1] = mny; sRedF[wave][2] = mnz;
        sRedF[wave][3] = mxx; sRedF[wave][4] = mxy; sRedF[wave][5] = mxz;
    }
    __syncthreads();
    if (t == 0) {
        double SX = 0, SY = 0, SZ = 0;
        float MN[3] = {INFINITY, INFINITY, INFINITY};
        float MX[3] = {-INFINITY, -INFINITY, -INFINITY};
        #pragma unroll
        for (int w = 0; w < 8; ++w) {
            SX += sRedD[w][0]; SY += sRedD[w][1]; SZ += sRedD[w][2];
            MN[0] = fminf(MN[0], sRedF[w][0]); MN[1] = fminf(MN[1], sRedF[w][1]); MN[2] = fminf(MN[2], sRedF[w][2]);
            MX[0] = fmaxf(MX[0], sRedF[w][3]); MX[1] = fmaxf(MX[1], sRedF[w][4]); MX[2] = fmaxf(MX[2], sRedF[w][5]);
        }
        double mean[3] = {0, 0, 0}, off[3] = {0, 0, 0}, scale = 50.0;
        if (n) {
            double dn = (double)n;
            mean[0] = SX / dn; mean[1] = SY / dn; mean[2] = SZ / dn;
            double r = 0.0, mn[3];
            #pragma unroll
            for (int d = 0; d < 3; ++d) {
                mn[d] = (double)MN[d] - mean[d];
                double mx = (double)MX[d] - mean[d];
                double ext = (mx - mn[d]) / (double)FS;
                r = fmax(r, ext);
            }
            double sr = 1.0 / r - 0.01;     // r==0 -> inf -> clamp to 50
            scale = fmin(sr, 50.0);
            #pragma unroll
            for (int d = 0; d < 3; ++d) off[d] = -(mn[d] * scale);
        }
        sPar[0] = mean[0]; sPar[1] = mean[1]; sPar[2] = mean[2];
        sPar[3] = scale;
        sPar[4] = off[0];  sPar[5] = off[1];  sPar[6] = off[2];
    }
    __syncthreads();
    double m0 = sPar[0], m1 = sPar[1], m2 = sPar[2];
    double sc = sPar[3], o0 = sPar[4], o1 = sPar[5], o2 = sPar[6];

    // ---- loop 2: voxel ids from registered coords; rank via LDS atomics ----
    uint vrR[K6];
    #pragma unroll
    for (int k = 0; k < K6; ++k) {
        int q = s0 + k * 512 + t;
        if (q < s1) {
            double vx = ((double)cxR[k] - m0) * sc + o0;
            double vy = ((double)cyR[k] - m1) * sc + o1;
            double vz = ((double)czR[k] - m2) * sc + o2;
            int ix = (int)floor(vx); ix = ix < 0 ? 0 : (ix > FS - 1 ? FS - 1 : ix);
            int iy = (int)floor(vy); iy = iy < 0 ? 0 : (iy > FS - 1 ? FS - 1 : iy);
            int iz = (int)floor(vz); iz = iz < 0 ? 0 : (iz > FS - 1 ? FS - 1 : iz);
            int v = (ix * FS + iy) * FS + iz;
            uint r = atomicAdd(&sCnt[v], 1u);
            vrR[k] = (r << 12) | (uint)v;          // r < 3072, v < 2744
        }
    }
    __syncthreads();

    // ---- block scan of 2744 counts -> local starts (in place) + global vptr ----
    {
        int b0 = t * K6;                 // 512*6 = 3072 >= F3
        uint loc[K6];
        uint run = 0;
        #pragma unroll
        for (int k = 0; k < K6; ++k) {
            int idx = b0 + k;
            uint x = (idx < F3) ? sCnt[idx] : 0u;
            loc[k] = run;
            run += x;
        }
        uint tot = run;
        #pragma unroll
        for (int d = 1; d < 64; d <<= 1) {
            uint y = __shfl_up(run, d, 64);
            if (lane >= d) run += y;
        }
        if (lane == 63) wsum[wave] = run;
        __syncthreads();
        uint woff = 0;
        #pragma unroll
        for (int i = 0; i < 8; ++i) if (i < wave) woff += wsum[i];
        uint excl = run - tot + woff;
        #pragma unroll
        for (int k = 0; k < K6; ++k) {
            int idx = b0 + k;
            if (idx < F3) {
                uint stv = excl + loc[k];
                sCnt[idx] = stv;                               // local start
                vptr[c * F3 + idx] = (uint)s0 + stv;           // global start
            }
        }
    }
    if (c == NC - 1 && t == 0) vptr[VOXT] = (uint)SPAIRS;      // sentinel
    if (t < 32) agg[c * 32 + t] = 0u;                          // agg-enc zero
    __syncthreads();

    // ---- loop 3: scatter own pairs from registers (no atomics, deterministic order per rank) ----
    #pragma unroll
    for (int k = 0; k < K6; ++k) {
        int q = s0 + k * 512 + t;
        if (q < s1) {
            uint vr = vrR[k];
            spid[(uint)s0 + sCnt[vr & 4095u] + (vr >> 12)] = pidR[k];
        }
    }
}

// ---------- kernel 2: float4 channel-group voxel mean + agg max (unchanged) ----------
__global__ __launch_bounds__(256) void k_out(const float4* __restrict__ feats4,
        const uint* __restrict__ vptr, const int* __restrict__ spid,
        float* __restrict__ out, uint* __restrict__ agg) {
    __shared__ uint  sVptr[344];
    __shared__ int   sPid[PCAP];
    __shared__ float sMxA[32][8][4];
    int b = blockIdx.x;
    int xcd = b & 7, r = b >> 3;
    int c = xcd * 32 + (r >> 3);     // cluster (XCD-swizzled)
    int p = r & 7;                   // eighth
    int t = threadIdx.x;
    int vid0 = c * F3 + p * STRIP;

    sVptr[t] = vptr[vid0 + t];
    if (t < 88) sVptr[256 + t] = vptr[vid0 + 256 + t];
    if (t == 0) sPid[0] = 0;                     // np==0 safety
    __syncthreads();
    uint S0 = sVptr[0], S1 = sVptr[343];
    int np = (int)(S1 - S0);
    bool fits = np <= PCAP;
    if (fits) for (int i = t; i < np; i += 256) sPid[i] = spid[S0 + i];
    __syncthreads();

    int vox = t >> 3;                // voxel slot 0..31
    int chg = t & 7;                 // float4 channel group
    float4 mx = make_float4(-INFINITY, -INFINITY, -INFINITY, -INFINITY);

    #pragma unroll 2
    for (int jb = 0; jb < 6; ++jb) {
        int v0 = vox + 64 * jb, v1 = v0 + 32;    // 12 strided voxels/thread total
        bool ok0 = v0 < STRIP, ok1 = v1 < STRIP;
        int vc0 = ok0 ? v0 : 342, vc1 = ok1 ? v1 : 342;
        uint s00 = sVptr[vc0]; uint cn0 = ok0 ? (sVptr[vc0 + 1] - s00) : 0u;
        uint s10 = sVptr[vc1]; uint cn1 = ok1 ? (sVptr[vc1 + 1] - s10) : 0u;
        uint i00 = s00 - S0, i10 = s10 - S0;
        uint a0 = (cn0 >= 1) ? i00 : 0u;  uint b0 = (cn0 >= 2) ? (i00 + 1) : a0;
        uint a1 = (cn1 >= 1) ? i10 : 0u;  uint b1 = (cn1 >= 2) ? (i10 + 1) : a1;
        int p00 = fits ? sPid[a0] : spid[S0 + a0];
        int p01 = fits ? sPid[b0] : spid[S0 + b0];
        int p10 = fits ? sPid[a1] : spid[S0 + a1];
        int p11 = fits ? sPid[b1] : spid[S0 + b1];
        float4 f00 = feats4[(uint)p00 * 8u + (uint)chg];   // 4 independent 16B loads
        float4 f01 = feats4[(uint)p01 * 8u + (uint)chg];
        float4 f10 = feats4[(uint)p10 * 8u + (uint)chg];
        float4 f11 = feats4[(uint)p11 * 8u + (uint)chg];

        float4 acc0, acc1;
        acc0.x = ((cn0 >= 1) ? f00.x : 0.f) + ((cn0 >= 2) ? f01.x : 0.f);
        acc0.y = ((cn0 >= 1) ? f00.y : 0.f) + ((cn0 >= 2) ? f01.y : 0.f);
        acc0.z = ((cn0 >= 1) ? f00.z : 0.f) + ((cn0 >= 2) ? f01.z : 0.f);
        acc0.w = ((cn0 >= 1) ? f00.w : 0.f) + ((cn0 >= 2) ? f01.w : 0.f);
        acc1.x = ((cn1 >= 1) ? f10.x : 0.f) + ((cn1 >= 2) ? f11.x : 0.f);
        acc1.y = ((cn1 >= 1) ? f10.y : 0.f) + ((cn1 >= 2) ? f11.y : 0.f);
        acc1.z = ((cn1 >= 1) ? f10.z : 0.f) + ((cn1 >= 2) ? f11.z : 0.f);
        acc1.w = ((cn1 >= 1) ? f10.w : 0.f) + ((cn1 >= 2) ? f11.w : 0.f);
        if (cn0 >= 1) { mx.x = fmaxf(mx.x, f00.x); mx.y = fmaxf(mx.y, f00.y); mx.z = fmaxf(mx.z, f00.z); mx.w = fmaxf(mx.w, f00.w); }
        if (cn0 >= 2) { mx.x = fmaxf(mx.x, f01.x); mx.y = fmaxf(mx.y, f01.y); mx.z = fmaxf(mx.z, f01.z); mx.w = fmaxf(mx.w, f01.w); }
        if (cn1 >= 1) { mx.x = fmaxf(mx.x, f10.x); mx.y = fmaxf(mx.y, f10.y); mx.z = fmaxf(mx.z, f10.z); mx.w = fmaxf(mx.w, f10.w); }
        if (cn1 >= 2) { mx.x = fmaxf(mx.x, f11.x); mx.y = fmaxf(mx.y, f11.y); mx.z = fmaxf(mx.z, f11.z); mx.w = fmaxf(mx.w, f11.w); }

        if (cn0 > 2) {                         // rare tails (~5.5% of voxels)
            for (uint q = 2; q < cn0; ++q) {
                int pq = fits ? sPid[i00 + q] : spid[S0 + i00 + q];
                float4 fq = feats4[(uint)pq * 8u + (uint)chg];
                acc0.x += fq.x; acc0.y += fq.y; acc0.z += fq.z; acc0.w += fq.w;
                mx.x = fmaxf(mx.x, fq.x); mx.y = fmaxf(mx.y, fq.y); mx.z = fmaxf(mx.z, fq.z); mx.w = fmaxf(mx.w, fq.w);
            }
        }
        if (cn1 > 2) {
            for (uint q = 2; q < cn1; ++q) {
                int pq = fits ? sPid[i10 + q] : spid[S0 + i10 + q];
                float4 fq = feats4[(uint)pq * 8u + (uint)chg];
                acc1.x += fq.x; acc1.y += fq.y; acc1.z += fq.z; acc1.w += fq.w;
                mx.x = fmaxf(mx.x, fq.x); mx.y = fmaxf(mx.y, fq.y); mx.z = fmaxf(mx.z, fq.z); mx.w = fmaxf(mx.w, fq.w);
            }
        }
        if (ok0) {
            float inv = __builtin_amdgcn_rcpf(cn0 ? (float)cn0 : 1.f);
            float4 rr; rr.x = acc0.x * inv; rr.y = acc0.y * inv; rr.z = acc0.z * inv; rr.w = acc0.w * inv;
            *(float4*)(out + (uint)(vid0 + v0) * 32u + (uint)chg * 4u) = rr;
        }
        if (ok1) {
            float inv = __builtin_amdgcn_rcpf(cn1 ? (float)cn1 : 1.f);
            float4 rr; rr.x = acc1.x * inv; rr.y = acc1.y * inv; rr.z = acc1.z * inv; rr.w = acc1.w * inv;
            *(float4*)(out + (uint)(vid0 + v1) * 32u + (uint)chg * 4u) = rr;
        }
    }

    sMxA[vox][chg][0] = mx.x; sMxA[vox][chg][1] = mx.y;
    sMxA[vox][chg][2] = mx.z; sMxA[vox][chg][3] = mx.w;
    __syncthreads();
    if (t < 32) {                    // t = channel; chg = t>>2, elem = t&3
        float m = -INFINITY;
        #pragma unroll
        for (int v = 0; v < 32; ++v) m = fmaxf(m, sMxA[v][t >> 2][t & 3]);
        if (m != -INFINITY) atomicMax(&agg[c * 32 + t], encF(m));
    }
}

// ---------- kernel 3: agg finalize (decode; untouched/neginf -> 0) ----------
__global__ void k_aggfin(float* outbase) {
    int i = blockIdx.x * blockDim.x + threadIdx.x;     // < NC*32 exactly
    uint* a = (uint*)(outbase + (size_t)VOXT * 32);
    uint e = a[i];
    float f = decF(e);
    if (e == 0u || f == -INFINITY) f = 0.0f;
    ((float*)a)[i] = f;
}

extern "C" void kernel_launch(void* const* d_in, const int* in_sizes, int n_in,
                              void* d_out, int out_size, void* d_ws, size_t ws_size,
                              hipStream_t stream) {
    const float* feats  = (const float*)d_in[0];
    const float* coords = (const float*)d_in[1];
    const void*  cids   = d_in[2];
    const void*  pids   = d_in[3];
    float* out = (float*)d_out;
    char* ws = (char*)d_ws;

    // ws layout (bytes), total 5,209,920 — no memsets, everything written by k_cluster:
    //   0         uint vptr[VOXT+1]   (2809860 -> pad 2809920)
    //   2809920   int  spid[SPAIRS]   (2400000) -> 5209920
    uint* vptr = (uint*)(ws + 0);
    int*  spid = (int*)(ws + 2809920);
    uint* agg  = (uint*)(out + (size_t)VOXT * 32);

    k_cluster<<<NC, 512, 0, stream>>>(cids, pids, coords, vptr, spid, agg);
    k_out<<<NBLK, 256, 0, stream>>>((const float4*)feats, vptr, spid, out, agg);
    k_aggfin<<<(NC * 32) / 256, 256, 0, stream>>>(out);
}